// Round 1
// baseline (1709.688 us; speedup 1.0000x reference)
//
#include <hip/hip_runtime.h>
#include <hip/hip_bf16.h>

// GCN_71451075936314 on gfx950.
// Pipeline: prep(bf16 casts/transposes) -> deg counting-sort -> XW=feat@Wih^T GEMM
//   -> LSTM recurrence (MFMA, Whh frags in regs, deg-sorted blocks, early exit)
//   -> SAGE fused GEMM(+relu+src-norm) -> neighbor-sum aggregate -> GraphConv GEMM
//   -> GRU GEMM+gates -> per-graph mean pool + classifier.
// All GEMM fragments use the guide-verified 16x16x32 bf16 MFMA layouts:
//   A[m=lane&15][k=quad*8+j], B[k=quad*8+j][n=lane&15], C/D: col=lane&15, row=quad*4+reg.

#define NN     50000
#define HIDD   128
#define MAXD   16
#define NGRAPH 50
#define NCLSS  10
#define GRUH   32

typedef __attribute__((ext_vector_type(8))) short s16x8;   // 8 bf16 carrier (4 VGPRs)
typedef __attribute__((ext_vector_type(4))) float f32x4;
typedef __hip_bfloat16 bf16;

#define MFMA16(a,b,c) __builtin_amdgcn_mfma_f32_16x16x32_bf16((a),(b),(c),0,0,0)

__device__ __forceinline__ float bf2f(bf16 x) { return __bfloat162float(x); }
__device__ __forceinline__ bf16  f2bf(float x) { return __float2bfloat16(x); }
__device__ __forceinline__ s16x8 ldfrag(const bf16* p) { return *(const s16x8*)p; }

__device__ __forceinline__ float sigf(float x) {
  return __builtin_amdgcn_rcpf(1.0f + __expf(-x));
}
__device__ __forceinline__ float tanhf_(float x) {
  // tanh(x) = 1 - 2/(1+e^{2x}); saturates gracefully at +-inf
  return 1.0f - 2.0f * __builtin_amdgcn_rcpf(1.0f + __expf(2.0f * x));
}

// ---------------- prep: bf16 casts + weight transposes + bias fold ----------------
__global__ void prep_kernel(const float* __restrict__ feat, const float* __restrict__ Wih,
                            const float* __restrict__ Whh, const float* __restrict__ bih,
                            const float* __restrict__ bhh, const float* __restrict__ Wself,
                            const float* __restrict__ Wneigh, const float* __restrict__ Wgc,
                            const float* __restrict__ Wgru,
                            bf16* featB, bf16* WihB, bf16* WhhB, bf16* WsT, bf16* WnT,
                            bf16* WgT, bf16* WgruB, float* biasS) {
  const int nf = NN * HIDD;                       // 6,400,000
  const int total = nf + 2 * 65536 + 3 * 16384 + 12288 + 512;
  int stride = gridDim.x * blockDim.x;
  for (int idx = blockIdx.x * blockDim.x + threadIdx.x; idx < total; idx += stride) {
    if (idx < nf) { featB[idx] = f2bf(feat[idx]); continue; }
    int j = idx - nf;
    if (j < 65536) { WihB[j] = f2bf(Wih[j]); continue; }
    j -= 65536;
    if (j < 65536) { WhhB[j] = f2bf(Whh[j]); continue; }
    j -= 65536;
    if (j < 16384) { int c = j >> 7, k = j & 127; WsT[j] = f2bf(Wself[k * HIDD + c]); continue; }
    j -= 16384;
    if (j < 16384) { int c = j >> 7, k = j & 127; WnT[j] = f2bf(Wneigh[k * HIDD + c]); continue; }
    j -= 16384;
    if (j < 16384) { int c = j >> 7, k = j & 127; WgT[j] = f2bf(Wgc[k * HIDD + c]); continue; }
    j -= 16384;
    if (j < 12288) { WgruB[j] = f2bf(Wgru[j]); continue; }
    j -= 12288;
    biasS[j] = bih[j] + bhh[j];
  }
}

// ---------------- counting sort of nodes by degree (16 bins) ----------------
__global__ void zero_hist_kernel(int* hist) {
  if (threadIdx.x < 17) hist[threadIdx.x] = 0;
}
__global__ void hist_kernel(const int* __restrict__ deg, int* hist) {
  for (int i = blockIdx.x * blockDim.x + threadIdx.x; i < NN; i += gridDim.x * blockDim.x)
    atomicAdd(&hist[deg[i]], 1);
}
__global__ void scan_kernel(const int* __restrict__ hist, int* offs) {
  if (blockIdx.x == 0 && threadIdx.x == 0) {
    int acc = 0;
    for (int d = 0; d < 17; ++d) { offs[d] = acc; acc += hist[d]; }
  }
}
__global__ void scatter_kernel(const int* __restrict__ deg, int* offs, int* perm) {
  for (int i = blockIdx.x * blockDim.x + threadIdx.x; i < NN; i += gridDim.x * blockDim.x) {
    int p = atomicAdd(&offs[deg[i]], 1);
    perm[p] = i;
  }
}

// ---------------- XW = feature @ Wih^T + (bih+bhh), bf16 out [NN,512] ----------------
__global__ __launch_bounds__(256) void xw_gemm_kernel(const bf16* __restrict__ featB,
                                                      const bf16* __restrict__ WihB,
                                                      const float* __restrict__ biasS,
                                                      bf16* __restrict__ XWb) {
  const int lane = threadIdx.x & 63, wave = threadIdx.x >> 6;
  const int l15 = lane & 15, quad = lane >> 4;
  const int nb = blockIdx.x * 64 + wave * 16;
  int arow = nb + l15; if (arow >= NN) arow = NN - 1;
  s16x8 A[4];
#pragma unroll
  for (int kt = 0; kt < 4; ++kt) A[kt] = ldfrag(featB + (size_t)arow * HIDD + kt * 32 + quad * 8);
  for (int ct = 0; ct < 32; ++ct) {
    const int col = ct * 16 + l15;
    f32x4 acc = {0.f, 0.f, 0.f, 0.f};
#pragma unroll
    for (int kt = 0; kt < 4; ++kt)
      acc = MFMA16(A[kt], ldfrag(WihB + col * HIDD + kt * 32 + quad * 8), acc);
    const float bb = biasS[col];
#pragma unroll
    for (int r = 0; r < 4; ++r) {
      const int node = nb + quad * 4 + r;
      if (node < NN) XWb[(size_t)node * 512 + col] = f2bf(acc[r] + bb);
    }
  }
}

// ---------------- LSTM recurrence over deg-sorted 32-node blocks ----------------
// 8 waves: wave = (ng<<2)|cg ; ng in {0,1} -> 16-node group; cg in 0..3 -> gate cols
// {128q + 32cg + 16u + l15}. Whh fragments (step-invariant) preloaded to registers.
__global__ __launch_bounds__(512, 2) void lstm_kernel(const bf16* __restrict__ XWb,
                                                      const bf16* __restrict__ WhhB,
                                                      const float* __restrict__ biasS,
                                                      const int* __restrict__ nbr_idx,
                                                      const int* __restrict__ deg,
                                                      const int* __restrict__ perm,
                                                      bf16* __restrict__ hTB) {
  __shared__ __align__(16) bf16 Hs[32 * 136];    // h tile, +8 pad per row (2-way LDS ok)
  __shared__ __align__(16) bf16 XWg[32 * 512];   // this step's gathered XW rows
  __shared__ int nodes_s[32];
  __shared__ int degs_s[32];

  const int tid = threadIdx.x;
  const int lane = tid & 63, wave = tid >> 6;
  const int l15 = lane & 15, quad = lane >> 4;
  const int ng = wave >> 2, cg = wave & 3;
  const int base = blockIdx.x * 32;

  if (tid < 32) {
    const int gi = base + tid;
    const int nd = (gi < NN) ? perm[gi] : -1;
    nodes_s[tid] = nd;
    degs_s[tid] = (nd >= 0) ? deg[nd] : 0;
  }
  for (int e = tid; e < 32 * 136; e += 512) Hs[e] = f2bf(0.0f);
  __syncthreads();

  const int lastValid = (base + 32 <= NN) ? 31 : (NN - 1 - base);
  const int maxdeg = degs_s[lastValid];          // sorted ascending -> block max

  int mydeg[4];
#pragma unroll
  for (int r = 0; r < 4; ++r) mydeg[r] = degs_s[ng * 16 + quad * 4 + r];

  float biasv[4][2];
  s16x8 Bf[4][2][4];
#pragma unroll
  for (int q = 0; q < 4; ++q)
#pragma unroll
    for (int u = 0; u < 2; ++u) {
      const int col = 128 * q + 32 * cg + 16 * u + l15;
      biasv[q][u] = biasS[col];
#pragma unroll
      for (int kt = 0; kt < 4; ++kt)
        Bf[q][u][kt] = ldfrag(WhhB + col * HIDD + kt * 32 + quad * 8);
    }

  float cst[2][4] = {{0.f, 0.f, 0.f, 0.f}, {0.f, 0.f, 0.f, 0.f}};
  const int arow = ng * 16 + l15;

  for (int t = 0; t < maxdeg; ++t) {
    __syncthreads();  // prev step's Hs writes / XWg reads complete
    // stage gathered XW rows (32 rows x 1KB) -> LDS; 4x 16B per thread
    s16x8 stg[4];
#pragma unroll
    for (int k = 0; k < 4; ++k) {
      const int i = tid + k * 512;
      const int row = i >> 6, cp = i & 63;
      const int nd = nodes_s[row];
      const int nbr = (nd >= 0) ? nbr_idx[nd * MAXD + t] : 0;
      stg[k] = ldfrag(XWb + (size_t)nbr * 512 + cp * 8);
    }
    // recurrent GEMM on previous h
    s16x8 Af[4];
#pragma unroll
    for (int kt = 0; kt < 4; ++kt)
      Af[kt] = *(const s16x8*)(Hs + arow * 136 + kt * 32 + quad * 8);
    f32x4 acc[4][2];
#pragma unroll
    for (int q = 0; q < 4; ++q)
#pragma unroll
      for (int u = 0; u < 2; ++u) {
        f32x4 a = {0.f, 0.f, 0.f, 0.f};
#pragma unroll
        for (int kt = 0; kt < 4; ++kt) a = MFMA16(Af[kt], Bf[q][u][kt], a);
        acc[q][u] = a;
      }
#pragma unroll
    for (int k = 0; k < 4; ++k)
      *(s16x8*)(XWg + (tid + k * 512) * 8) = stg[k];
    __syncthreads();  // XWg visible; Hs A-reads done
    // elementwise LSTM cell (i,f,g,o = q 0..3)
#pragma unroll
    for (int u = 0; u < 2; ++u)
#pragma unroll
      for (int r = 0; r < 4; ++r) {
        const int row = ng * 16 + quad * 4 + r;
        const int cb = 32 * cg + 16 * u + l15;
        const bf16* xr = XWg + row * 512 + cb;
        const float g_i = acc[0][u][r] + bf2f(xr[0])   + biasv[0][u];
        const float g_f = acc[1][u][r] + bf2f(xr[128]) + biasv[1][u];
        const float g_g = acc[2][u][r] + bf2f(xr[256]) + biasv[2][u];
        const float g_o = acc[3][u][r] + bf2f(xr[384]) + biasv[3][u];
        const float iv = sigf(g_i), fv = sigf(g_f);
        const float gv = tanhf_(g_g), ov = sigf(g_o);
        const float cn = fv * cst[u][r] + iv * gv;
        const float hn = ov * tanhf_(cn);
        if (t < mydeg[r]) {
          cst[u][r] = cn;
          Hs[row * 136 + cb] = f2bf(hn);
        }
      }
  }
  __syncthreads();
  for (int e = tid; e < 32 * 16; e += 512) {
    const int row = e >> 4, c8 = (e & 15) * 8;
    const int nd = nodes_s[row];
    if (nd >= 0)
      *(s16x8*)(hTB + (size_t)nd * HIDD + c8) = *(const s16x8*)(Hs + row * 136 + c8);
  }
}

// ------- SAGE: h1n = relu(feat@W_self + hT@W_neigh + b) * rsqrt(deg)  (src-norm fused) -------
__global__ __launch_bounds__(256) void sage_kernel(const bf16* __restrict__ featB,
                                                   const bf16* __restrict__ hTB,
                                                   const bf16* __restrict__ WsT,
                                                   const bf16* __restrict__ WnT,
                                                   const float* __restrict__ b_sage,
                                                   const int* __restrict__ deg,
                                                   bf16* __restrict__ h1n) {
  const int lane = threadIdx.x & 63, wave = threadIdx.x >> 6;
  const int l15 = lane & 15, quad = lane >> 4;
  const int nb = blockIdx.x * 64 + wave * 16;
  int arow = nb + l15; if (arow >= NN) arow = NN - 1;
  s16x8 Fa[4], Ha[4];
#pragma unroll
  for (int kt = 0; kt < 4; ++kt) {
    Fa[kt] = ldfrag(featB + (size_t)arow * HIDD + kt * 32 + quad * 8);
    Ha[kt] = ldfrag(hTB + (size_t)arow * HIDD + kt * 32 + quad * 8);
  }
  int nodes[4]; float nrm[4];
#pragma unroll
  for (int r = 0; r < 4; ++r) {
    const int nd = nb + quad * 4 + r;
    nodes[r] = nd;
    nrm[r] = rsqrtf((float)deg[(nd < NN) ? nd : (NN - 1)]);
  }
  for (int ct = 0; ct < 8; ++ct) {
    const int col = ct * 16 + l15;
    f32x4 acc = {0.f, 0.f, 0.f, 0.f};
#pragma unroll
    for (int kt = 0; kt < 4; ++kt) {
      acc = MFMA16(Fa[kt], ldfrag(WsT + col * HIDD + kt * 32 + quad * 8), acc);
      acc = MFMA16(Ha[kt], ldfrag(WnT + col * HIDD + kt * 32 + quad * 8), acc);
    }
    const float bb = b_sage[col];
#pragma unroll
    for (int r = 0; r < 4; ++r)
      if (nodes[r] < NN) {
        const float v = fmaxf(acc[r] + bb, 0.f) * nrm[r];
        h1n[(size_t)nodes[r] * HIDD + col] = f2bf(v);
      }
  }
}

// ------- GraphConv aggregate: agg[n] = rsqrt(deg[n]) * sum_{t<deg} h1n[nbr[n,t]] -------
__global__ __launch_bounds__(256) void agg_kernel(const bf16* __restrict__ h1n,
                                                  const int* __restrict__ nbr_idx,
                                                  const int* __restrict__ deg,
                                                  bf16* __restrict__ aggB) {
  const int wave = threadIdx.x >> 6, lane = threadIdx.x & 63;
  const int node = blockIdx.x * 4 + wave;
  if (node >= NN) return;
  const int d = deg[node];
  const int c = lane * 2;
  float a0 = 0.f, a1 = 0.f;
  for (int t = 0; t < d; ++t) {
    const int nbr = nbr_idx[node * MAXD + t];
    const __hip_bfloat162 v = *(const __hip_bfloat162*)(h1n + (size_t)nbr * HIDD + c);
    a0 += __bfloat162float(v.x);
    a1 += __bfloat162float(v.y);
  }
  const float nm = rsqrtf((float)d);
  aggB[(size_t)node * HIDD + c]     = f2bf(a0 * nm);
  aggB[(size_t)node * HIDD + c + 1] = f2bf(a1 * nm);
}

// ------- GraphConv GEMM: h2 = relu(agg @ W_gc + b_gc) -------
__global__ __launch_bounds__(256) void gc_gemm_kernel(const bf16* __restrict__ aggB,
                                                      const bf16* __restrict__ WgT,
                                                      const float* __restrict__ b_gc,
                                                      bf16* __restrict__ h2B) {
  const int lane = threadIdx.x & 63, wave = threadIdx.x >> 6;
  const int l15 = lane & 15, quad = lane >> 4;
  const int nb = blockIdx.x * 64 + wave * 16;
  int arow = nb + l15; if (arow >= NN) arow = NN - 1;
  s16x8 A[4];
#pragma unroll
  for (int kt = 0; kt < 4; ++kt) A[kt] = ldfrag(aggB + (size_t)arow * HIDD + kt * 32 + quad * 8);
  for (int ct = 0; ct < 8; ++ct) {
    const int col = ct * 16 + l15;
    f32x4 acc = {0.f, 0.f, 0.f, 0.f};
#pragma unroll
    for (int kt = 0; kt < 4; ++kt)
      acc = MFMA16(A[kt], ldfrag(WgT + col * HIDD + kt * 32 + quad * 8), acc);
    const float bb = b_gc[col];
#pragma unroll
    for (int r = 0; r < 4; ++r) {
      const int node = nb + quad * 4 + r;
      if (node < NN) h2B[(size_t)node * HIDD + col] = f2bf(fmaxf(acc[r] + bb, 0.f));
    }
  }
}

// ------- GRU (seq_len=1, h0=0): out = (1-z)*tanh(xn + r*bn) -------
__global__ __launch_bounds__(256) void gru_kernel(const bf16* __restrict__ h2B,
                                                  const bf16* __restrict__ WgruB,
                                                  const float* __restrict__ bih,
                                                  const float* __restrict__ bhh,
                                                  float* __restrict__ gout) {
  const int lane = threadIdx.x & 63, wave = threadIdx.x >> 6;
  const int l15 = lane & 15, quad = lane >> 4;
  const int nb = blockIdx.x * 64 + wave * 16;
  int arow = nb + l15; if (arow >= NN) arow = NN - 1;
  s16x8 A[4];
#pragma unroll
  for (int kt = 0; kt < 4; ++kt) A[kt] = ldfrag(h2B + (size_t)arow * HIDD + kt * 32 + quad * 8);
  f32x4 acc[6];
#pragma unroll
  for (int ct = 0; ct < 6; ++ct) {
    f32x4 a = {0.f, 0.f, 0.f, 0.f};
#pragma unroll
    for (int kt = 0; kt < 4; ++kt)
      a = MFMA16(A[kt], ldfrag(WgruB + (ct * 16 + l15) * HIDD + kt * 32 + quad * 8), a);
    acc[ct] = a;
  }
#pragma unroll
  for (int u = 0; u < 2; ++u) {
    const int cu = 16 * u + l15;
    const float br = bih[cu] + bhh[cu];
    const float bz = bih[32 + cu] + bhh[32 + cu];
    const float bni = bih[64 + cu];
    const float bnh = bhh[64 + cu];
#pragma unroll
    for (int r = 0; r < 4; ++r) {
      const int node = nb + quad * 4 + r;
      if (node < NN) {
        const float rv = sigf(acc[u][r] + br);
        const float zv = sigf(acc[2 + u][r] + bz);
        const float nv = tanhf_(acc[4 + u][r] + bni + rv * bnh);
        gout[(size_t)node * GRUH + cu] = (1.f - zv) * nv;
      }
    }
  }
}

// ------- per-graph mean pool + classifier -------
__global__ __launch_bounds__(256) void pool_kernel(const float* __restrict__ gout,
                                                   const int* __restrict__ gids,
                                                   const float* __restrict__ Wcls,
                                                   const float* __restrict__ bcls,
                                                   float* __restrict__ out) {
  __shared__ float sums[8][32];
  __shared__ float cnts[8];
  __shared__ float hg[32];
  const int b = blockIdx.x;
  const int c = threadIdx.x & 31, g = threadIdx.x >> 5;
  float s = 0.f; int cnt = 0;
  for (int n = g; n < NN; n += 8) {
    if (gids[n] == b) { s += gout[(size_t)n * GRUH + c]; ++cnt; }
  }
  sums[g][c] = s;
  if (c == 0) cnts[g] = (float)cnt;
  __syncthreads();
  if (threadIdx.x < 32) {
    float tot = 0.f, tc = 0.f;
    for (int gg = 0; gg < 8; ++gg) { tot += sums[gg][threadIdx.x]; tc += cnts[gg]; }
    hg[threadIdx.x] = tot / tc;
  }
  __syncthreads();
  if (threadIdx.x < NCLSS) {
    float acc = bcls[threadIdx.x];
    for (int cc = 0; cc < GRUH; ++cc) acc += hg[cc] * Wcls[cc * NCLSS + threadIdx.x];
    out[b * NCLSS + threadIdx.x] = acc;
  }
}

extern "C" void kernel_launch(void* const* d_in, const int* in_sizes, int n_in,
                              void* d_out, int out_size, void* d_ws, size_t ws_size,
                              hipStream_t stream) {
  const float* feature  = (const float*)d_in[0];
  const int*   nbr_idx  = (const int*)d_in[1];
  const int*   deg      = (const int*)d_in[2];
  const int*   gids     = (const int*)d_in[3];
  const float* lstm_Wih = (const float*)d_in[4];
  const float* lstm_Whh = (const float*)d_in[5];
  const float* lstm_bih = (const float*)d_in[6];
  const float* lstm_bhh = (const float*)d_in[7];
  const float* W_self   = (const float*)d_in[8];
  const float* W_neigh  = (const float*)d_in[9];
  const float* b_sage   = (const float*)d_in[10];
  const float* W_gc     = (const float*)d_in[11];
  const float* b_gc     = (const float*)d_in[12];
  const float* Wih_gru  = (const float*)d_in[13];
  const float* bih_gru  = (const float*)d_in[14];
  const float* bhh_gru  = (const float*)d_in[15];
  const float* W_cls    = (const float*)d_in[16];
  const float* b_cls    = (const float*)d_in[17];

  // workspace layout (peak ~90.3 MB; aliases chosen on producer/consumer order)
  char* ws = (char*)d_ws;
  bf16*  XWb   = (bf16*)(ws + 0);           // [NN,512] bf16, 51.2 MB (dead after lstm)
  bf16*  featB = (bf16*)(ws + 51200000);    // [NN,128] bf16 (dead after sage)
  bf16*  hTB   = (bf16*)(ws + 64000000);    // [NN,128] bf16 (dead after sage)
  bf16*  h1nB  = (bf16*)(ws + 76800000);    // [NN,128] bf16
  bf16*  aggB  = featB;                     // alias: written after featB dead
  bf16*  h2B   = XWb;                       // alias: written after XWb dead
  float* gout  = (float*)(ws + 64000000);   // alias hTB: written after hTB dead
  const size_t wo = 89600000;
  bf16*  WihB  = (bf16*)(ws + wo);
  bf16*  WhhB  = (bf16*)(ws + wo + 131072);
  bf16*  WsT   = (bf16*)(ws + wo + 262144);
  bf16*  WnT   = (bf16*)(ws + wo + 294912);
  bf16*  WgT   = (bf16*)(ws + wo + 327680);
  bf16*  WgruB = (bf16*)(ws + wo + 360448);
  float* biasS = (float*)(ws + wo + 385024);
  int*   perm  = (int*)(ws + 90000000);
  int*   hist  = (int*)(ws + 90200000);
  int*   offs  = (int*)(ws + 90200128);

  prep_kernel<<<3072, 256, 0, stream>>>(feature, lstm_Wih, lstm_Whh, lstm_bih, lstm_bhh,
                                        W_self, W_neigh, W_gc, Wih_gru,
                                        featB, WihB, WhhB, WsT, WnT, WgT, WgruB, biasS);
  zero_hist_kernel<<<1, 32, 0, stream>>>(hist);
  hist_kernel<<<196, 256, 0, stream>>>(deg, hist);
  scan_kernel<<<1, 64, 0, stream>>>(hist, offs);
  scatter_kernel<<<196, 256, 0, stream>>>(deg, offs, perm);
  xw_gemm_kernel<<<782, 256, 0, stream>>>(featB, WihB, biasS, XWb);
  lstm_kernel<<<1563, 512, 0, stream>>>(XWb, WhhB, biasS, nbr_idx, deg, perm, hTB);
  sage_kernel<<<782, 256, 0, stream>>>(featB, hTB, WsT, WnT, b_sage, deg, h1nB);
  agg_kernel<<<12500, 256, 0, stream>>>(h1nB, nbr_idx, deg, aggB);
  gc_gemm_kernel<<<782, 256, 0, stream>>>(aggB, WgT, b_gc, h2B);
  gru_kernel<<<782, 256, 0, stream>>>(h2B, WgruB, bih_gru, bhh_gru, gout);
  pool_kernel<<<NGRAPH, 256, 0, stream>>>(gout, gids, W_cls, b_cls, (float*)d_out);
}

// Round 2
// 859.291 us; speedup vs baseline: 1.9896x; 1.9896x over previous
//
#include <hip/hip_runtime.h>
#include <hip/hip_bf16.h>

// GCN_71451075936314 on gfx950.
// Pipeline: prep(bf16 casts/transposes) -> deg counting-sort -> XW=feat@Wih^T GEMM
//   -> LSTM recurrence (MFMA, Whh frags in regs, deg-sorted blocks, early exit)
//   -> SAGE fused GEMM(+relu+src-norm) -> neighbor-sum aggregate -> GraphConv GEMM
//   -> GRU GEMM+gates -> two-phase per-graph mean pool + classifier.
// R1 change: pool was 50-block serial scan (990us, 55% of total) -> two-phase
//   LDS-partial reduction (98 blocks, flush-on-graph-change) + tiny final GEMM.

#define NN     50000
#define HIDD   128
#define MAXD   16
#define NGRAPH 50
#define NCLSS  10
#define GRUH   32

typedef __attribute__((ext_vector_type(8))) short s16x8;   // 8 bf16 carrier (4 VGPRs)
typedef __attribute__((ext_vector_type(4))) float f32x4;
typedef __hip_bfloat16 bf16;

#define MFMA16(a,b,c) __builtin_amdgcn_mfma_f32_16x16x32_bf16((a),(b),(c),0,0,0)

__device__ __forceinline__ float bf2f(bf16 x) { return __bfloat162float(x); }
__device__ __forceinline__ bf16  f2bf(float x) { return __float2bfloat16(x); }
__device__ __forceinline__ s16x8 ldfrag(const bf16* p) { return *(const s16x8*)p; }

__device__ __forceinline__ float sigf(float x) {
  return __builtin_amdgcn_rcpf(1.0f + __expf(-x));
}
__device__ __forceinline__ float tanhf_(float x) {
  // tanh(x) = 1 - 2/(1+e^{2x}); saturates gracefully at +-inf
  return 1.0f - 2.0f * __builtin_amdgcn_rcpf(1.0f + __expf(2.0f * x));
}

// ---------------- prep: bf16 casts + weight transposes + bias fold ----------------
__global__ void prep_kernel(const float* __restrict__ feat, const float* __restrict__ Wih,
                            const float* __restrict__ Whh, const float* __restrict__ bih,
                            const float* __restrict__ bhh, const float* __restrict__ Wself,
                            const float* __restrict__ Wneigh, const float* __restrict__ Wgc,
                            const float* __restrict__ Wgru,
                            bf16* featB, bf16* WihB, bf16* WhhB, bf16* WsT, bf16* WnT,
                            bf16* WgT, bf16* WgruB, float* biasS) {
  const int nf = NN * HIDD;                       // 6,400,000
  const int total = nf + 2 * 65536 + 3 * 16384 + 12288 + 512;
  int stride = gridDim.x * blockDim.x;
  for (int idx = blockIdx.x * blockDim.x + threadIdx.x; idx < total; idx += stride) {
    if (idx < nf) { featB[idx] = f2bf(feat[idx]); continue; }
    int j = idx - nf;
    if (j < 65536) { WihB[j] = f2bf(Wih[j]); continue; }
    j -= 65536;
    if (j < 65536) { WhhB[j] = f2bf(Whh[j]); continue; }
    j -= 65536;
    if (j < 16384) { int c = j >> 7, k = j & 127; WsT[j] = f2bf(Wself[k * HIDD + c]); continue; }
    j -= 16384;
    if (j < 16384) { int c = j >> 7, k = j & 127; WnT[j] = f2bf(Wneigh[k * HIDD + c]); continue; }
    j -= 16384;
    if (j < 16384) { int c = j >> 7, k = j & 127; WgT[j] = f2bf(Wgc[k * HIDD + c]); continue; }
    j -= 16384;
    if (j < 12288) { WgruB[j] = f2bf(Wgru[j]); continue; }
    j -= 12288;
    biasS[j] = bih[j] + bhh[j];
  }
}

// ---------------- counting sort of nodes by degree (16 bins) ----------------
__global__ void zero_hist_kernel(int* hist) {
  if (threadIdx.x < 17) hist[threadIdx.x] = 0;
}
__global__ void hist_kernel(const int* __restrict__ deg, int* hist) {
  for (int i = blockIdx.x * blockDim.x + threadIdx.x; i < NN; i += gridDim.x * blockDim.x)
    atomicAdd(&hist[deg[i]], 1);
}
__global__ void scan_kernel(const int* __restrict__ hist, int* offs) {
  if (blockIdx.x == 0 && threadIdx.x == 0) {
    int acc = 0;
    for (int d = 0; d < 17; ++d) { offs[d] = acc; acc += hist[d]; }
  }
}
__global__ void scatter_kernel(const int* __restrict__ deg, int* offs, int* perm) {
  for (int i = blockIdx.x * blockDim.x + threadIdx.x; i < NN; i += gridDim.x * blockDim.x) {
    int p = atomicAdd(&offs[deg[i]], 1);
    perm[p] = i;
  }
}

// ---------------- XW = feature @ Wih^T + (bih+bhh), bf16 out [NN,512] ----------------
__global__ __launch_bounds__(256) void xw_gemm_kernel(const bf16* __restrict__ featB,
                                                      const bf16* __restrict__ WihB,
                                                      const float* __restrict__ biasS,
                                                      bf16* __restrict__ XWb) {
  const int lane = threadIdx.x & 63, wave = threadIdx.x >> 6;
  const int l15 = lane & 15, quad = lane >> 4;
  const int nb = blockIdx.x * 64 + wave * 16;
  int arow = nb + l15; if (arow >= NN) arow = NN - 1;
  s16x8 A[4];
#pragma unroll
  for (int kt = 0; kt < 4; ++kt) A[kt] = ldfrag(featB + (size_t)arow * HIDD + kt * 32 + quad * 8);
  for (int ct = 0; ct < 32; ++ct) {
    const int col = ct * 16 + l15;
    f32x4 acc = {0.f, 0.f, 0.f, 0.f};
#pragma unroll
    for (int kt = 0; kt < 4; ++kt)
      acc = MFMA16(A[kt], ldfrag(WihB + col * HIDD + kt * 32 + quad * 8), acc);
    const float bb = biasS[col];
#pragma unroll
    for (int r = 0; r < 4; ++r) {
      const int node = nb + quad * 4 + r;
      if (node < NN) XWb[(size_t)node * 512 + col] = f2bf(acc[r] + bb);
    }
  }
}

// ---------------- LSTM recurrence over deg-sorted 32-node blocks ----------------
// 8 waves: wave = (ng<<2)|cg ; ng in {0,1} -> 16-node group; cg in 0..3 -> gate cols
// {128q + 32cg + 16u + l15}. Whh fragments (step-invariant) preloaded to registers.
__global__ __launch_bounds__(512, 2) void lstm_kernel(const bf16* __restrict__ XWb,
                                                      const bf16* __restrict__ WhhB,
                                                      const float* __restrict__ biasS,
                                                      const int* __restrict__ nbr_idx,
                                                      const int* __restrict__ deg,
                                                      const int* __restrict__ perm,
                                                      bf16* __restrict__ hTB) {
  __shared__ __align__(16) bf16 Hs[32 * 136];    // h tile, +8 pad per row (2-way LDS ok)
  __shared__ __align__(16) bf16 XWg[32 * 512];   // this step's gathered XW rows
  __shared__ int nodes_s[32];
  __shared__ int degs_s[32];

  const int tid = threadIdx.x;
  const int lane = tid & 63, wave = tid >> 6;
  const int l15 = lane & 15, quad = lane >> 4;
  const int ng = wave >> 2, cg = wave & 3;
  const int base = blockIdx.x * 32;

  if (tid < 32) {
    const int gi = base + tid;
    const int nd = (gi < NN) ? perm[gi] : -1;
    nodes_s[tid] = nd;
    degs_s[tid] = (nd >= 0) ? deg[nd] : 0;
  }
  for (int e = tid; e < 32 * 136; e += 512) Hs[e] = f2bf(0.0f);
  __syncthreads();

  const int lastValid = (base + 32 <= NN) ? 31 : (NN - 1 - base);
  const int maxdeg = degs_s[lastValid];          // sorted ascending -> block max

  int mydeg[4];
#pragma unroll
  for (int r = 0; r < 4; ++r) mydeg[r] = degs_s[ng * 16 + quad * 4 + r];

  float biasv[4][2];
  s16x8 Bf[4][2][4];
#pragma unroll
  for (int q = 0; q < 4; ++q)
#pragma unroll
    for (int u = 0; u < 2; ++u) {
      const int col = 128 * q + 32 * cg + 16 * u + l15;
      biasv[q][u] = biasS[col];
#pragma unroll
      for (int kt = 0; kt < 4; ++kt)
        Bf[q][u][kt] = ldfrag(WhhB + col * HIDD + kt * 32 + quad * 8);
    }

  float cst[2][4] = {{0.f, 0.f, 0.f, 0.f}, {0.f, 0.f, 0.f, 0.f}};
  const int arow = ng * 16 + l15;

  for (int t = 0; t < maxdeg; ++t) {
    __syncthreads();  // prev step's Hs writes / XWg reads complete
    // stage gathered XW rows (32 rows x 1KB) -> LDS; 4x 16B per thread
    s16x8 stg[4];
#pragma unroll
    for (int k = 0; k < 4; ++k) {
      const int i = tid + k * 512;
      const int row = i >> 6, cp = i & 63;
      const int nd = nodes_s[row];
      const int nbr = (nd >= 0) ? nbr_idx[nd * MAXD + t] : 0;
      stg[k] = ldfrag(XWb + (size_t)nbr * 512 + cp * 8);
    }
    // recurrent GEMM on previous h
    s16x8 Af[4];
#pragma unroll
    for (int kt = 0; kt < 4; ++kt)
      Af[kt] = *(const s16x8*)(Hs + arow * 136 + kt * 32 + quad * 8);
    f32x4 acc[4][2];
#pragma unroll
    for (int q = 0; q < 4; ++q)
#pragma unroll
      for (int u = 0; u < 2; ++u) {
        f32x4 a = {0.f, 0.f, 0.f, 0.f};
#pragma unroll
        for (int kt = 0; kt < 4; ++kt) a = MFMA16(Af[kt], Bf[q][u][kt], a);
        acc[q][u] = a;
      }
#pragma unroll
    for (int k = 0; k < 4; ++k)
      *(s16x8*)(XWg + (tid + k * 512) * 8) = stg[k];
    __syncthreads();  // XWg visible; Hs A-reads done
    // elementwise LSTM cell (i,f,g,o = q 0..3)
#pragma unroll
    for (int u = 0; u < 2; ++u)
#pragma unroll
      for (int r = 0; r < 4; ++r) {
        const int row = ng * 16 + quad * 4 + r;
        const int cb = 32 * cg + 16 * u + l15;
        const bf16* xr = XWg + row * 512 + cb;
        const float g_i = acc[0][u][r] + bf2f(xr[0])   + biasv[0][u];
        const float g_f = acc[1][u][r] + bf2f(xr[128]) + biasv[1][u];
        const float g_g = acc[2][u][r] + bf2f(xr[256]) + biasv[2][u];
        const float g_o = acc[3][u][r] + bf2f(xr[384]) + biasv[3][u];
        const float iv = sigf(g_i), fv = sigf(g_f);
        const float gv = tanhf_(g_g), ov = sigf(g_o);
        const float cn = fv * cst[u][r] + iv * gv;
        const float hn = ov * tanhf_(cn);
        if (t < mydeg[r]) {
          cst[u][r] = cn;
          Hs[row * 136 + cb] = f2bf(hn);
        }
      }
  }
  __syncthreads();
  for (int e = tid; e < 32 * 16; e += 512) {
    const int row = e >> 4, c8 = (e & 15) * 8;
    const int nd = nodes_s[row];
    if (nd >= 0)
      *(s16x8*)(hTB + (size_t)nd * HIDD + c8) = *(const s16x8*)(Hs + row * 136 + c8);
  }
}

// ------- SAGE: h1n = relu(feat@W_self + hT@W_neigh + b) * rsqrt(deg)  (src-norm fused) -------
__global__ __launch_bounds__(256) void sage_kernel(const bf16* __restrict__ featB,
                                                   const bf16* __restrict__ hTB,
                                                   const bf16* __restrict__ WsT,
                                                   const bf16* __restrict__ WnT,
                                                   const float* __restrict__ b_sage,
                                                   const int* __restrict__ deg,
                                                   bf16* __restrict__ h1n) {
  const int lane = threadIdx.x & 63, wave = threadIdx.x >> 6;
  const int l15 = lane & 15, quad = lane >> 4;
  const int nb = blockIdx.x * 64 + wave * 16;
  int arow = nb + l15; if (arow >= NN) arow = NN - 1;
  s16x8 Fa[4], Ha[4];
#pragma unroll
  for (int kt = 0; kt < 4; ++kt) {
    Fa[kt] = ldfrag(featB + (size_t)arow * HIDD + kt * 32 + quad * 8);
    Ha[kt] = ldfrag(hTB + (size_t)arow * HIDD + kt * 32 + quad * 8);
  }
  int nodes[4]; float nrm[4];
#pragma unroll
  for (int r = 0; r < 4; ++r) {
    const int nd = nb + quad * 4 + r;
    nodes[r] = nd;
    nrm[r] = rsqrtf((float)deg[(nd < NN) ? nd : (NN - 1)]);
  }
  for (int ct = 0; ct < 8; ++ct) {
    const int col = ct * 16 + l15;
    f32x4 acc = {0.f, 0.f, 0.f, 0.f};
#pragma unroll
    for (int kt = 0; kt < 4; ++kt) {
      acc = MFMA16(Fa[kt], ldfrag(WsT + col * HIDD + kt * 32 + quad * 8), acc);
      acc = MFMA16(Ha[kt], ldfrag(WnT + col * HIDD + kt * 32 + quad * 8), acc);
    }
    const float bb = b_sage[col];
#pragma unroll
    for (int r = 0; r < 4; ++r)
      if (nodes[r] < NN) {
        const float v = fmaxf(acc[r] + bb, 0.f) * nrm[r];
        h1n[(size_t)nodes[r] * HIDD + col] = f2bf(v);
      }
  }
}

// ------- GraphConv aggregate: agg[n] = rsqrt(deg[n]) * sum_{t<deg} h1n[nbr[n,t]] -------
__global__ __launch_bounds__(256) void agg_kernel(const bf16* __restrict__ h1n,
                                                  const int* __restrict__ nbr_idx,
                                                  const int* __restrict__ deg,
                                                  bf16* __restrict__ aggB) {
  const int wave = threadIdx.x >> 6, lane = threadIdx.x & 63;
  const int node = blockIdx.x * 4 + wave;
  if (node >= NN) return;
  const int d = deg[node];
  const int c = lane * 2;
  float a0 = 0.f, a1 = 0.f;
  for (int t = 0; t < d; ++t) {
    const int nbr = nbr_idx[node * MAXD + t];
    const __hip_bfloat162 v = *(const __hip_bfloat162*)(h1n + (size_t)nbr * HIDD + c);
    a0 += __bfloat162float(v.x);
    a1 += __bfloat162float(v.y);
  }
  const float nm = rsqrtf((float)d);
  aggB[(size_t)node * HIDD + c]     = f2bf(a0 * nm);
  aggB[(size_t)node * HIDD + c + 1] = f2bf(a1 * nm);
}

// ------- GraphConv GEMM: h2 = relu(agg @ W_gc + b_gc) -------
__global__ __launch_bounds__(256) void gc_gemm_kernel(const bf16* __restrict__ aggB,
                                                      const bf16* __restrict__ WgT,
                                                      const float* __restrict__ b_gc,
                                                      bf16* __restrict__ h2B) {
  const int lane = threadIdx.x & 63, wave = threadIdx.x >> 6;
  const int l15 = lane & 15, quad = lane >> 4;
  const int nb = blockIdx.x * 64 + wave * 16;
  int arow = nb + l15; if (arow >= NN) arow = NN - 1;
  s16x8 A[4];
#pragma unroll
  for (int kt = 0; kt < 4; ++kt) A[kt] = ldfrag(aggB + (size_t)arow * HIDD + kt * 32 + quad * 8);
  for (int ct = 0; ct < 8; ++ct) {
    const int col = ct * 16 + l15;
    f32x4 acc = {0.f, 0.f, 0.f, 0.f};
#pragma unroll
    for (int kt = 0; kt < 4; ++kt)
      acc = MFMA16(A[kt], ldfrag(WgT + col * HIDD + kt * 32 + quad * 8), acc);
    const float bb = b_gc[col];
#pragma unroll
    for (int r = 0; r < 4; ++r) {
      const int node = nb + quad * 4 + r;
      if (node < NN) h2B[(size_t)node * HIDD + col] = f2bf(fmaxf(acc[r] + bb, 0.f));
    }
  }
}

// ------- GRU (seq_len=1, h0=0): out = (1-z)*tanh(xn + r*bn) -------
__global__ __launch_bounds__(256) void gru_kernel(const bf16* __restrict__ h2B,
                                                  const bf16* __restrict__ WgruB,
                                                  const float* __restrict__ bih,
                                                  const float* __restrict__ bhh,
                                                  float* __restrict__ gout) {
  const int lane = threadIdx.x & 63, wave = threadIdx.x >> 6;
  const int l15 = lane & 15, quad = lane >> 4;
  const int nb = blockIdx.x * 64 + wave * 16;
  int arow = nb + l15; if (arow >= NN) arow = NN - 1;
  s16x8 A[4];
#pragma unroll
  for (int kt = 0; kt < 4; ++kt) A[kt] = ldfrag(h2B + (size_t)arow * HIDD + kt * 32 + quad * 8);
  f32x4 acc[6];
#pragma unroll
  for (int ct = 0; ct < 6; ++ct) {
    f32x4 a = {0.f, 0.f, 0.f, 0.f};
#pragma unroll
    for (int kt = 0; kt < 4; ++kt)
      a = MFMA16(A[kt], ldfrag(WgruB + (ct * 16 + l15) * HIDD + kt * 32 + quad * 8), a);
    acc[ct] = a;
  }
#pragma unroll
  for (int u = 0; u < 2; ++u) {
    const int cu = 16 * u + l15;
    const float br = bih[cu] + bhh[cu];
    const float bz = bih[32 + cu] + bhh[32 + cu];
    const float bni = bih[64 + cu];
    const float bnh = bhh[64 + cu];
#pragma unroll
    for (int r = 0; r < 4; ++r) {
      const int node = nb + quad * 4 + r;
      if (node < NN) {
        const float rv = sigf(acc[u][r] + br);
        const float zv = sigf(acc[2 + u][r] + bz);
        const float nv = tanhf_(acc[4 + u][r] + bni + rv * bnh);
        gout[(size_t)node * GRUH + cu] = (1.f - zv) * nv;
      }
    }
  }
}

// ------- two-phase per-graph mean pool + classifier -------
__global__ void zero_pool_kernel(float* sums, float* cnts) {
  const int tid = threadIdx.x;
  for (int i = tid; i < NGRAPH * GRUH; i += 256) sums[i] = 0.f;
  if (tid < NGRAPH) cnts[tid] = 0.f;
}

// phase 1: each block reduces a contiguous 512-node chunk into LDS per-graph
// partials. graph_ids is monotone non-decreasing, so register accumulation with
// flush-on-graph-change makes LDS atomics rare (~1 graph boundary per chunk).
#define POOL_CHUNK 512
__global__ __launch_bounds__(256) void pool_partial_kernel(const float* __restrict__ gout,
                                                           const int* __restrict__ gids,
                                                           float* __restrict__ sums,
                                                           float* __restrict__ cnts) {
  __shared__ float ls[NGRAPH * GRUH];
  __shared__ float lc[NGRAPH];
  const int tid = threadIdx.x;
  for (int i = tid; i < NGRAPH * GRUH; i += 256) ls[i] = 0.f;
  if (tid < NGRAPH) lc[tid] = 0.f;
  __syncthreads();

  const int wave = tid >> 6, lane = tid & 63;
  const int c = lane & 31, half = lane >> 5;      // 2 nodes per wave-iter
  const int base = blockIdx.x * POOL_CHUNK + wave * (POOL_CHUNK / 8);

  float accv = 0.f, ccnt = 0.f;
  int curg = -1;
  for (int it = 0; it < POOL_CHUNK / 16; ++it) {  // 32 iters x 2 nodes
    const int n = base + it * 2 + half;
    if (n < NN) {
      const int g = gids[n];
      const float v = gout[(size_t)n * GRUH + c];
      if (g != curg) {
        if (curg >= 0) {
          atomicAdd(&ls[curg * GRUH + c], accv);
          if (c == 0) atomicAdd(&lc[curg], ccnt);
        }
        curg = g; accv = 0.f; ccnt = 0.f;
      }
      accv += v; ccnt += 1.f;
    }
  }
  if (curg >= 0) {
    atomicAdd(&ls[curg * GRUH + c], accv);
    if (c == 0) atomicAdd(&lc[curg], ccnt);
  }
  __syncthreads();
  for (int i = tid; i < NGRAPH * GRUH; i += 256)
    if (ls[i] != 0.f) atomicAdd(&sums[i], ls[i]);
  if (tid < NGRAPH && lc[tid] != 0.f) atomicAdd(&cnts[tid], lc[tid]);
}

// phase 2: hg = sums/cnt ; out = hg @ W_cls + b_cls  (500 outputs)
__global__ __launch_bounds__(256) void pool_final_kernel(const float* __restrict__ sums,
                                                         const float* __restrict__ cnts,
                                                         const float* __restrict__ Wcls,
                                                         const float* __restrict__ bcls,
                                                         float* __restrict__ out) {
  const int idx = blockIdx.x * blockDim.x + threadIdx.x;
  if (idx >= NGRAPH * NCLSS) return;
  const int g = idx / NCLSS, k = idx % NCLSS;
  const float inv = 1.0f / cnts[g];
  float acc = bcls[k];
#pragma unroll
  for (int cc = 0; cc < GRUH; ++cc)
    acc += sums[g * GRUH + cc] * inv * Wcls[cc * NCLSS + k];
  out[idx] = acc;
}

extern "C" void kernel_launch(void* const* d_in, const int* in_sizes, int n_in,
                              void* d_out, int out_size, void* d_ws, size_t ws_size,
                              hipStream_t stream) {
  const float* feature  = (const float*)d_in[0];
  const int*   nbr_idx  = (const int*)d_in[1];
  const int*   deg      = (const int*)d_in[2];
  const int*   gids     = (const int*)d_in[3];
  const float* lstm_Wih = (const float*)d_in[4];
  const float* lstm_Whh = (const float*)d_in[5];
  const float* lstm_bih = (const float*)d_in[6];
  const float* lstm_bhh = (const float*)d_in[7];
  const float* W_self   = (const float*)d_in[8];
  const float* W_neigh  = (const float*)d_in[9];
  const float* b_sage   = (const float*)d_in[10];
  const float* W_gc     = (const float*)d_in[11];
  const float* b_gc     = (const float*)d_in[12];
  const float* Wih_gru  = (const float*)d_in[13];
  const float* bih_gru  = (const float*)d_in[14];
  const float* bhh_gru  = (const float*)d_in[15];
  const float* W_cls    = (const float*)d_in[16];
  const float* b_cls    = (const float*)d_in[17];

  // workspace layout (peak ~90.3 MB; aliases chosen on producer/consumer order)
  char* ws = (char*)d_ws;
  bf16*  XWb   = (bf16*)(ws + 0);           // [NN,512] bf16, 51.2 MB (dead after lstm)
  bf16*  featB = (bf16*)(ws + 51200000);    // [NN,128] bf16 (dead after sage)
  bf16*  hTB   = (bf16*)(ws + 64000000);    // [NN,128] bf16 (dead after sage)
  bf16*  h1nB  = (bf16*)(ws + 76800000);    // [NN,128] bf16
  bf16*  aggB  = featB;                     // alias: written after featB dead
  bf16*  h2B   = XWb;                       // alias: written after XWb dead
  float* gout  = (float*)(ws + 64000000);   // alias hTB: written after hTB dead
  const size_t wo = 89600000;
  bf16*  WihB  = (bf16*)(ws + wo);
  bf16*  WhhB  = (bf16*)(ws + wo + 131072);
  bf16*  WsT   = (bf16*)(ws + wo + 262144);
  bf16*  WnT   = (bf16*)(ws + wo + 294912);
  bf16*  WgT   = (bf16*)(ws + wo + 327680);
  bf16*  WgruB = (bf16*)(ws + wo + 360448);
  float* biasS = (float*)(ws + wo + 385024);
  int*   perm  = (int*)(ws + 90000000);
  int*   hist  = (int*)(ws + 90200000);
  int*   offs  = (int*)(ws + 90200128);
  float* psums = (float*)(ws + 90201216);   // [50][32]
  float* pcnts = (float*)(ws + 90201216 + NGRAPH * GRUH * 4);

  prep_kernel<<<3072, 256, 0, stream>>>(feature, lstm_Wih, lstm_Whh, lstm_bih, lstm_bhh,
                                        W_self, W_neigh, W_gc, Wih_gru,
                                        featB, WihB, WhhB, WsT, WnT, WgT, WgruB, biasS);
  zero_hist_kernel<<<1, 32, 0, stream>>>(hist);
  hist_kernel<<<196, 256, 0, stream>>>(deg, hist);
  scan_kernel<<<1, 64, 0, stream>>>(hist, offs);
  scatter_kernel<<<196, 256, 0, stream>>>(deg, offs, perm);
  xw_gemm_kernel<<<782, 256, 0, stream>>>(featB, WihB, biasS, XWb);
  lstm_kernel<<<1563, 512, 0, stream>>>(XWb, WhhB, biasS, nbr_idx, deg, perm, hTB);
  sage_kernel<<<782, 256, 0, stream>>>(featB, hTB, WsT, WnT, b_sage, deg, h1nB);
  agg_kernel<<<12500, 256, 0, stream>>>(h1nB, nbr_idx, deg, aggB);
  gc_gemm_kernel<<<782, 256, 0, stream>>>(aggB, WgT, b_gc, h2B);
  gru_kernel<<<782, 256, 0, stream>>>(h2B, WgruB, bih_gru, bhh_gru, gout);
  zero_pool_kernel<<<1, 256, 0, stream>>>(psums, pcnts);
  pool_partial_kernel<<<(NN + POOL_CHUNK - 1) / POOL_CHUNK, 256, 0, stream>>>(gout, gids, psums, pcnts);
  pool_final_kernel<<<2, 256, 0, stream>>>(psums, pcnts, W_cls, b_cls, (float*)d_out);
}

// Round 4
// 665.699 us; speedup vs baseline: 2.5683x; 1.2908x over previous
//
#include <hip/hip_runtime.h>
#include <hip/hip_bf16.h>

// GCN_71451075936314 on gfx950.
// R4: fix R3's global_load_lds misuse — the GLOBAL source address is PER-LANE
//     (vaddr), LDS dst is wave-uniform base + lane*16B. R3 passed a uniform
//     gptr, so every staged XW row was 64 copies of cols 0..7 (absmax 5.1e-3).
//     Now each lane supplies grow + lane*8 bf16 (16B). Everything else
//     unchanged from R3 for clean attribution:
//     - lstm: 32x32x16 MFMA, Whh frags asm-pinned, double-buffered gl2lds
//       prefetch one step ahead, lgkm-only barrier, XOR-swizzled Hs, t=0 skip.
//     - hist/scatter: LDS histograms. agg: shfl-broadcast indices.

#define NN     50000
#define HIDD   128
#define MAXD   16
#define NGRAPH 50
#define NCLSS  10
#define GRUH   32

typedef __attribute__((ext_vector_type(8))) short s16x8;    // 8 bf16 (4 VGPRs)
typedef __attribute__((ext_vector_type(4))) float f32x4;
typedef __attribute__((ext_vector_type(16))) float f32x16;
typedef __hip_bfloat16 bf16;

#define MFMA16(a,b,c)  __builtin_amdgcn_mfma_f32_16x16x32_bf16((a),(b),(c),0,0,0)
#define MFMA32(a,b,c)  __builtin_amdgcn_mfma_f32_32x32x16_bf16((a),(b),(c),0,0,0)

__device__ __forceinline__ float bf2f(bf16 x) { return __bfloat162float(x); }
__device__ __forceinline__ bf16  f2bf(float x) { return __float2bfloat16(x); }
__device__ __forceinline__ s16x8 ldfrag(const bf16* p) { return *(const s16x8*)p; }

__device__ __forceinline__ float sigf(float x) {
  return __builtin_amdgcn_rcpf(1.0f + __expf(-x));
}
__device__ __forceinline__ float tanhf_(float x) {
  return 1.0f - 2.0f * __builtin_amdgcn_rcpf(1.0f + __expf(2.0f * x));
}

// async global->LDS, one 512-bf16 row per wave-call:
// lane i loads grow[lane*8 .. lane*8+7] (16B) -> lrow + lane*16B (hw scatter).
__device__ __forceinline__ void gl2lds_row(const bf16* grow, bf16* lrow, int lane) {
  __builtin_amdgcn_global_load_lds(
      (const __attribute__((address_space(1))) unsigned int*)(grow + lane * 8),
      (__attribute__((address_space(3))) unsigned int*)lrow, 16, 0, 0);
}
// barrier that drains LDS ops but keeps global_load_lds prefetch in flight
__device__ __forceinline__ void lgkm_barrier() {
  asm volatile("s_waitcnt lgkmcnt(0)\n\ts_barrier" ::: "memory");
}

// ---------------- prep: bf16 casts + weight transposes + bias fold ----------------
__global__ void prep_kernel(const float* __restrict__ feat, const float* __restrict__ Wih,
                            const float* __restrict__ Whh, const float* __restrict__ bih,
                            const float* __restrict__ bhh, const float* __restrict__ Wself,
                            const float* __restrict__ Wneigh, const float* __restrict__ Wgc,
                            const float* __restrict__ Wgru,
                            bf16* featB, bf16* WihB, bf16* WhhB, bf16* WsT, bf16* WnT,
                            bf16* WgT, bf16* WgruB, float* biasS) {
  const int nf = NN * HIDD;
  const int total = nf + 2 * 65536 + 3 * 16384 + 12288 + 512;
  int stride = gridDim.x * blockDim.x;
  for (int idx = blockIdx.x * blockDim.x + threadIdx.x; idx < total; idx += stride) {
    if (idx < nf) { featB[idx] = f2bf(feat[idx]); continue; }
    int j = idx - nf;
    if (j < 65536) { WihB[j] = f2bf(Wih[j]); continue; }
    j -= 65536;
    if (j < 65536) { WhhB[j] = f2bf(Whh[j]); continue; }
    j -= 65536;
    if (j < 16384) { int c = j >> 7, k = j & 127; WsT[j] = f2bf(Wself[k * HIDD + c]); continue; }
    j -= 16384;
    if (j < 16384) { int c = j >> 7, k = j & 127; WnT[j] = f2bf(Wneigh[k * HIDD + c]); continue; }
    j -= 16384;
    if (j < 16384) { int c = j >> 7, k = j & 127; WgT[j] = f2bf(Wgc[k * HIDD + c]); continue; }
    j -= 16384;
    if (j < 12288) { WgruB[j] = f2bf(Wgru[j]); continue; }
    j -= 12288;
    biasS[j] = bih[j] + bhh[j];
  }
}

// ---------------- counting sort by degree: LDS hist -> per-block reservation ----------------
__global__ __launch_bounds__(256) void hist_kernel(const int* __restrict__ deg, int* hist) {
  __shared__ int lh[17];
  const int tid = threadIdx.x;
  if (tid < 17) lh[tid] = 0;
  __syncthreads();
  const int i = blockIdx.x * 256 + tid;
  if (i < NN) atomicAdd(&lh[deg[i]], 1);
  __syncthreads();
  if (tid < 17 && lh[tid]) atomicAdd(&hist[tid], lh[tid]);
}

__global__ __launch_bounds__(256) void scatter_kernel(const int* __restrict__ deg,
                                                      const int* __restrict__ hist,
                                                      int* __restrict__ resv,
                                                      int* __restrict__ perm) {
  __shared__ int lh[17], lbase[17], lpos[17];
  const int tid = threadIdx.x;
  if (tid < 17) { lh[tid] = 0; lpos[tid] = 0; }
  __syncthreads();
  const int i = blockIdx.x * 256 + tid;
  const int d = (i < NN) ? deg[i] : -1;
  if (d >= 0) atomicAdd(&lh[d], 1);
  __syncthreads();
  if (tid < 17) {
    int pre = 0;
    for (int k = 0; k < tid; ++k) pre += hist[k];
    lbase[tid] = pre + (lh[tid] ? atomicAdd(&resv[tid], lh[tid]) : 0);
  }
  __syncthreads();
  if (d >= 0) {
    const int p = lbase[d] + atomicAdd(&lpos[d], 1);
    perm[p] = i;
  }
}

// ---------------- XW = feature @ Wih^T + (bih+bhh), bf16 out [NN,512] ----------------
__global__ __launch_bounds__(256) void xw_gemm_kernel(const bf16* __restrict__ featB,
                                                      const bf16* __restrict__ WihB,
                                                      const float* __restrict__ biasS,
                                                      bf16* __restrict__ XWb) {
  const int lane = threadIdx.x & 63, wave = threadIdx.x >> 6;
  const int l15 = lane & 15, quad = lane >> 4;
  const int nb = blockIdx.x * 64 + wave * 16;
  int arow = nb + l15; if (arow >= NN) arow = NN - 1;
  s16x8 A[4];
#pragma unroll
  for (int kt = 0; kt < 4; ++kt) A[kt] = ldfrag(featB + (size_t)arow * HIDD + kt * 32 + quad * 8);
  for (int ct = 0; ct < 32; ++ct) {
    const int col = ct * 16 + l15;
    f32x4 acc = {0.f, 0.f, 0.f, 0.f};
#pragma unroll
    for (int kt = 0; kt < 4; ++kt)
      acc = MFMA16(A[kt], ldfrag(WihB + col * HIDD + kt * 32 + quad * 8), acc);
    const float bb = biasS[col];
#pragma unroll
    for (int r = 0; r < 4; ++r) {
      const int node = nb + quad * 4 + r;
      if (node < NN) XWb[(size_t)node * 512 + col] = f2bf(acc[r] + bb);
    }
  }
}

// ---------------- LSTM recurrence: 256 thr / 32 nodes / 4 waves ----------------
// Wave w owns elem-cols ec = w*32+l31 for ALL 4 gates (cols q*128+ec).
// Whh frags pinned in VGPRs; XW rows DMA'd via global_load_lds one step ahead.
// Hs stored XOR-swizzled: elem e of row m at  m*128 + (e ^ ((m&15)*8)).
__global__ __launch_bounds__(256, 2) void lstm_kernel(const bf16* __restrict__ XWb,
                                                      const bf16* __restrict__ WhhB,
                                                      const float* __restrict__ biasS,
                                                      const int* __restrict__ nbr_idx,
                                                      const int* __restrict__ deg,
                                                      const int* __restrict__ perm,
                                                      bf16* __restrict__ hTB) {
  __shared__ __align__(16) bf16 XWg[2 * 32 * 512];  // double-buffered gathered rows, 64KB
  __shared__ __align__(16) bf16 Hs[32 * 128];       // h tile, xor-swizzled, 8KB
  __shared__ int nbr_s[32 * 16];
  __shared__ int nodes_s[32];
  __shared__ int degs_s[32];

  const int tid = threadIdx.x;
  const int lane = tid & 63, wave = tid >> 6;       // wave = elem-col block
  const int l31 = lane & 31, hi = lane >> 5;
  const int base = blockIdx.x * 32;
  const int ec = wave * 32 + l31;                   // elem col 0..127

  if (tid < 32) {
    const int gi = base + tid;
    const int nd = (gi < NN) ? perm[gi] : -1;
    nodes_s[tid] = nd;
    degs_s[tid] = (nd >= 0) ? deg[nd] : 0;
  }
  __syncthreads();
  // fill neighbor table + zero Hs
  for (int e = tid; e < 32 * 16; e += 256) {
    const int row = e >> 4, t = e & 15;
    const int nd = nodes_s[row];
    nbr_s[e] = (nd >= 0) ? nbr_idx[nd * MAXD + t] : 0;
  }
  for (int e = tid; e < 32 * 64; e += 256) ((unsigned int*)Hs)[e] = 0u;

  const int lastValid = (base + 32 <= NN) ? 31 : (NN - 1 - base);

  // Whh fragments: 4 gates x 8 k-tiles, pinned so they can't be rematerialized
  s16x8 Bf[4][8];
#pragma unroll
  for (int q = 0; q < 4; ++q)
#pragma unroll
    for (int kt = 0; kt < 8; ++kt) {
      Bf[q][kt] = ldfrag(WhhB + (q * 128 + ec) * HIDD + kt * 16 + hi * 8);
      asm volatile("" : "+v"(Bf[q][kt]));
    }
  float bias_q[4];
#pragma unroll
  for (int q = 0; q < 4; ++q) bias_q[q] = biasS[q * 128 + ec];

  __syncthreads();
  const int maxdeg = degs_s[lastValid];             // sorted ascending -> block max

  // prologue: prefetch t=0 rows into buffer 0 (per-lane global src!)
  {
    bf16* dst = XWg;
#pragma unroll
    for (int rr = 0; rr < 8; ++rr) {
      const int row = wave * 8 + rr;
      const int nbr = __builtin_amdgcn_readfirstlane(nbr_s[row * 16]);
      gl2lds_row(XWb + (size_t)nbr * 512, dst + row * 512, lane);
    }
  }

  float cst[16];
#pragma unroll
  for (int r = 0; r < 16; ++r) cst[r] = 0.f;

  for (int t = 0; t < maxdeg; ++t) {
    f32x16 acc[4];
#pragma unroll
    for (int q = 0; q < 4; ++q) acc[q] = (f32x16)(0.f);
    if (t > 0) {
      // recurrent GEMM: gates += h_{t-1} @ Whh^T
#pragma unroll
      for (int kt = 0; kt < 8; ++kt) {
        const int k = kt * 16 + hi * 8;
        const s16x8 a = ldfrag(Hs + l31 * 128 + (k ^ ((l31 & 15) * 8)));
#pragma unroll
        for (int q = 0; q < 4; ++q) acc[q] = MFMA32(a, Bf[q][kt], acc[q]);
      }
    }
    __syncthreads();  // drains prefetch of buffer t&1 (vmcnt0); Af reads done before Hs writes
    // prefetch t+1 (stays in flight across the lgkm-only barrier below)
    if (t + 1 < maxdeg) {
      bf16* dst = XWg + ((t + 1) & 1) * (32 * 512);
#pragma unroll
      for (int rr = 0; rr < 8; ++rr) {
        const int row = wave * 8 + rr;
        const int nbr = __builtin_amdgcn_readfirstlane(nbr_s[row * 16 + t + 1]);
        gl2lds_row(XWb + (size_t)nbr * 512, dst + row * 512, lane);
      }
    }
    // elementwise LSTM cell
    const bf16* XWc = XWg + (t & 1) * (32 * 512);
#pragma unroll
    for (int reg = 0; reg < 16; ++reg) {
      const int m = (reg & 3) + 8 * (reg >> 2) + 4 * hi;   // 32x32 C/D row mapping
      const float g_i = acc[0][reg] + bf2f(XWc[m * 512 + 0 * 128 + ec]) + bias_q[0];
      const float g_f = acc[1][reg] + bf2f(XWc[m * 512 + 1 * 128 + ec]) + bias_q[1];
      const float g_g = acc[2][reg] + bf2f(XWc[m * 512 + 2 * 128 + ec]) + bias_q[2];
      const float g_o = acc[3][reg] + bf2f(XWc[m * 512 + 3 * 128 + ec]) + bias_q[3];
      const float iv = sigf(g_i), fv = sigf(g_f);
      const float gv = tanhf_(g_g), ov = sigf(g_o);
      const float cn = fv * cst[reg] + iv * gv;
      const float hn = ov * tanhf_(cn);
      if (t < degs_s[m]) {
        cst[reg] = cn;
        Hs[m * 128 + (ec ^ ((m & 15) * 8))] = f2bf(hn);
      }
    }
    lgkm_barrier();   // Hs visible; prefetch still in flight
  }

  // epilogue: Hs (swizzled) -> hTB
  for (int e = tid; e < 32 * 16; e += 256) {
    const int row = e >> 4, j = e & 15;
    const int nd = nodes_s[row];
    if (nd >= 0) {
      const s16x8 v = ldfrag(Hs + row * 128 + ((j * 8) ^ ((row & 15) * 8)));
      *(s16x8*)(hTB + (size_t)nd * HIDD + j * 8) = v;
    }
  }
}

// ------- SAGE: h1n = relu(feat@W_self + hT@W_neigh + b) * rsqrt(deg) -------
__global__ __launch_bounds__(256) void sage_kernel(const bf16* __restrict__ featB,
                                                   const bf16* __restrict__ hTB,
                                                   const bf16* __restrict__ WsT,
                                                   const bf16* __restrict__ WnT,
                                                   const float* __restrict__ b_sage,
                                                   const int* __restrict__ deg,
                                                   bf16* __restrict__ h1n) {
  const int lane = threadIdx.x & 63, wave = threadIdx.x >> 6;
  const int l15 = lane & 15, quad = lane >> 4;
  const int nb = blockIdx.x * 64 + wave * 16;
  int arow = nb + l15; if (arow >= NN) arow = NN - 1;
  s16x8 Fa[4], Ha[4];
#pragma unroll
  for (int kt = 0; kt < 4; ++kt) {
    Fa[kt] = ldfrag(featB + (size_t)arow * HIDD + kt * 32 + quad * 8);
    Ha[kt] = ldfrag(hTB + (size_t)arow * HIDD + kt * 32 + quad * 8);
  }
  int nodes[4]; float nrm[4];
#pragma unroll
  for (int r = 0; r < 4; ++r) {
    const int nd = nb + quad * 4 + r;
    nodes[r] = nd;
    nrm[r] = rsqrtf((float)deg[(nd < NN) ? nd : (NN - 1)]);
  }
  for (int ct = 0; ct < 8; ++ct) {
    const int col = ct * 16 + l15;
    f32x4 acc = {0.f, 0.f, 0.f, 0.f};
#pragma unroll
    for (int kt = 0; kt < 4; ++kt) {
      acc = MFMA16(Fa[kt], ldfrag(WsT + col * HIDD + kt * 32 + quad * 8), acc);
      acc = MFMA16(Ha[kt], ldfrag(WnT + col * HIDD + kt * 32 + quad * 8), acc);
    }
    const float bb = b_sage[col];
#pragma unroll
    for (int r = 0; r < 4; ++r)
      if (nodes[r] < NN) {
        const float v = fmaxf(acc[r] + bb, 0.f) * nrm[r];
        h1n[(size_t)nodes[r] * HIDD + col] = f2bf(v);
      }
  }
}

// ------- GraphConv aggregate: agg[n] = rsqrt(deg[n]) * sum_{t<deg} h1n[nbr[n,t]] -------
__global__ __launch_bounds__(256) void agg_kernel(const bf16* __restrict__ h1n,
                                                  const int* __restrict__ nbr_idx,
                                                  const int* __restrict__ deg,
                                                  bf16* __restrict__ aggB) {
  const int wave = threadIdx.x >> 6, lane = threadIdx.x & 63;
  const int node = blockIdx.x * 4 + wave;
  if (node >= NN) return;
  const int d = deg[node];
  const int idx_l = nbr_idx[node * MAXD + (lane & 15)];   // coalesced, broadcast via shfl
  const int c = lane * 2;
  float a0 = 0.f, a1 = 0.f;
  for (int t = 0; t < d; ++t) {
    const int nbr = __shfl(idx_l, t, 64);
    const __hip_bfloat162 v = *(const __hip_bfloat162*)(h1n + (size_t)nbr * HIDD + c);
    a0 += __bfloat162float(v.x);
    a1 += __bfloat162float(v.y);
  }
  const float nm = rsqrtf((float)d);
  aggB[(size_t)node * HIDD + c]     = f2bf(a0 * nm);
  aggB[(size_t)node * HIDD + c + 1] = f2bf(a1 * nm);
}

// ------- GraphConv GEMM: h2 = relu(agg @ W_gc + b_gc) -------
__global__ __launch_bounds__(256) void gc_gemm_kernel(const bf16* __restrict__ aggB,
                                                      const bf16* __restrict__ WgT,
                                                      const float* __restrict__ b_gc,
                                                      bf16* __restrict__ h2B) {
  const int lane = threadIdx.x & 63, wave = threadIdx.x >> 6;
  const int l15 = lane & 15, quad = lane >> 4;
  const int nb = blockIdx.x * 64 + wave * 16;
  int arow = nb + l15; if (arow >= NN) arow = NN - 1;
  s16x8 A[4];
#pragma unroll
  for (int kt = 0; kt < 4; ++kt) A[kt] = ldfrag(aggB + (size_t)arow * HIDD + kt * 32 + quad * 8);
  for (int ct = 0; ct < 8; ++ct) {
    const int col = ct * 16 + l15;
    f32x4 acc = {0.f, 0.f, 0.f, 0.f};
#pragma unroll
    for (int kt = 0; kt < 4; ++kt)
      acc = MFMA16(A[kt], ldfrag(WgT + col * HIDD + kt * 32 + quad * 8), acc);
    const float bb = b_gc[col];
#pragma unroll
    for (int r = 0; r < 4; ++r) {
      const int node = nb + quad * 4 + r;
      if (node < NN) h2B[(size_t)node * HIDD + col] = f2bf(fmaxf(acc[r] + bb, 0.f));
    }
  }
}

// ------- GRU (seq_len=1, h0=0): out = (1-z)*tanh(xn + r*bn) -------
__global__ __launch_bounds__(256) void gru_kernel(const bf16* __restrict__ h2B,
                                                  const bf16* __restrict__ WgruB,
                                                  const float* __restrict__ bih,
                                                  const float* __restrict__ bhh,
                                                  float* __restrict__ gout) {
  const int lane = threadIdx.x & 63, wave = threadIdx.x >> 6;
  const int l15 = lane & 15, quad = lane >> 4;
  const int nb = blockIdx.x * 64 + wave * 16;
  int arow = nb + l15; if (arow >= NN) arow = NN - 1;
  s16x8 A[4];
#pragma unroll
  for (int kt = 0; kt < 4; ++kt) A[kt] = ldfrag(h2B + (size_t)arow * HIDD + kt * 32 + quad * 8);
  f32x4 acc[6];
#pragma unroll
  for (int ct = 0; ct < 6; ++ct) {
    f32x4 a = {0.f, 0.f, 0.f, 0.f};
#pragma unroll
    for (int kt = 0; kt < 4; ++kt)
      a = MFMA16(A[kt], ldfrag(WgruB + (ct * 16 + l15) * HIDD + kt * 32 + quad * 8), a);
    acc[ct] = a;
  }
#pragma unroll
  for (int u = 0; u < 2; ++u) {
    const int cu = 16 * u + l15;
    const float br = bih[cu] + bhh[cu];
    const float bz = bih[32 + cu] + bhh[32 + cu];
    const float bni = bih[64 + cu];
    const float bnh = bhh[64 + cu];
#pragma unroll
    for (int r = 0; r < 4; ++r) {
      const int node = nb + quad * 4 + r;
      if (node < NN) {
        const float rv = sigf(acc[u][r] + br);
        const float zv = sigf(acc[2 + u][r] + bz);
        const float nv = tanhf_(acc[4 + u][r] + bni + rv * bnh);
        gout[(size_t)node * GRUH + cu] = (1.f - zv) * nv;
      }
    }
  }
}

// ------- two-phase per-graph mean pool + classifier -------
#define POOL_CHUNK 512
__global__ __launch_bounds__(256) void pool_partial_kernel(const float* __restrict__ gout,
                                                           const int* __restrict__ gids,
                                                           float* __restrict__ sums,
                                                           float* __restrict__ cnts) {
  __shared__ float ls[NGRAPH * GRUH];
  __shared__ float lc[NGRAPH];
  const int tid = threadIdx.x;
  for (int i = tid; i < NGRAPH * GRUH; i += 256) ls[i] = 0.f;
  if (tid < NGRAPH) lc[tid] = 0.f;
  __syncthreads();

  const int wave = tid >> 6, lane = tid & 63;
  const int c = lane & 31, half = lane >> 5;
  const int base = blockIdx.x * POOL_CHUNK + wave * (POOL_CHUNK / 8);

  float accv = 0.f, ccnt = 0.f;
  int curg = -1;
  for (int it = 0; it < POOL_CHUNK / 16; ++it) {
    const int n = base + it * 2 + half;
    if (n < NN) {
      const int g = gids[n];
      const float v = gout[(size_t)n * GRUH + c];
      if (g != curg) {
        if (curg >= 0) {
          atomicAdd(&ls[curg * GRUH + c], accv);
          if (c == 0) atomicAdd(&lc[curg], ccnt);
        }
        curg = g; accv = 0.f; ccnt = 0.f;
      }
      accv += v; ccnt += 1.f;
    }
  }
  if (curg >= 0) {
    atomicAdd(&ls[curg * GRUH + c], accv);
    if (c == 0) atomicAdd(&lc[curg], ccnt);
  }
  __syncthreads();
  for (int i = tid; i < NGRAPH * GRUH; i += 256)
    if (ls[i] != 0.f) atomicAdd(&sums[i], ls[i]);
  if (tid < NGRAPH && lc[tid] != 0.f) atomicAdd(&cnts[tid], lc[tid]);
}

__global__ __launch_bounds__(256) void pool_final_kernel(const float* __restrict__ sums,
                                                         const float* __restrict__ cnts,
                                                         const float* __restrict__ Wcls,
                                                         const float* __restrict__ bcls,
                                                         float* __restrict__ out) {
  const int idx = blockIdx.x * blockDim.x + threadIdx.x;
  if (idx >= NGRAPH * NCLSS) return;
  const int g = idx / NCLSS, k = idx % NCLSS;
  const float inv = 1.0f / cnts[g];
  float acc = bcls[k];
#pragma unroll
  for (int cc = 0; cc < GRUH; ++cc)
    acc += sums[g * GRUH + cc] * inv * Wcls[cc * NCLSS + k];
  out[idx] = acc;
}

extern "C" void kernel_launch(void* const* d_in, const int* in_sizes, int n_in,
                              void* d_out, int out_size, void* d_ws, size_t ws_size,
                              hipStream_t stream) {
  const float* feature  = (const float*)d_in[0];
  const int*   nbr_idx  = (const int*)d_in[1];
  const int*   deg      = (const int*)d_in[2];
  const int*   gids     = (const int*)d_in[3];
  const float* lstm_Wih = (const float*)d_in[4];
  const float* lstm_Whh = (const float*)d_in[5];
  const float* lstm_bih = (const float*)d_in[6];
  const float* lstm_bhh = (const float*)d_in[7];
  const float* W_self   = (const float*)d_in[8];
  const float* W_neigh  = (const float*)d_in[9];
  const float* b_sage   = (const float*)d_in[10];
  const float* W_gc     = (const float*)d_in[11];
  const float* b_gc     = (const float*)d_in[12];
  const float* Wih_gru  = (const float*)d_in[13];
  const float* bih_gru  = (const float*)d_in[14];
  const float* bhh_gru  = (const float*)d_in[15];
  const float* W_cls    = (const float*)d_in[16];
  const float* b_cls    = (const float*)d_in[17];

  char* ws = (char*)d_ws;
  bf16*  XWb   = (bf16*)(ws + 0);           // [NN,512] bf16, 51.2 MB (dead after lstm)
  bf16*  featB = (bf16*)(ws + 51200000);    // [NN,128] (dead after sage)
  bf16*  hTB   = (bf16*)(ws + 64000000);    // [NN,128] (dead after sage)
  bf16*  h1nB  = (bf16*)(ws + 76800000);    // [NN,128]
  bf16*  aggB  = featB;                     // alias
  bf16*  h2B   = XWb;                       // alias
  float* gout  = (float*)(ws + 64000000);   // alias hTB
  const size_t wo = 89600000;
  bf16*  WihB  = (bf16*)(ws + wo);
  bf16*  WhhB  = (bf16*)(ws + wo + 131072);
  bf16*  WsT   = (bf16*)(ws + wo + 262144);
  bf16*  WnT   = (bf16*)(ws + wo + 294912);
  bf16*  WgT   = (bf16*)(ws + wo + 327680);
  bf16*  WgruB = (bf16*)(ws + wo + 360448);
  float* biasS = (float*)(ws + wo + 385024);
  int*   perm  = (int*)(ws + 90000000);
  int*   hist  = (int*)(ws + 90200192);     // [17]
  int*   resv  = hist + 17;                 // [17]
  float* psums = (float*)(ws + 90201216);   // [50][32]
  float* pcnts = psums + NGRAPH * GRUH;     // [50]

  prep_kernel<<<3072, 256, 0, stream>>>(feature, lstm_Wih, lstm_Whh, lstm_bih, lstm_bhh,
                                        W_self, W_neigh, W_gc, Wih_gru,
                                        featB, WihB, WhhB, WsT, WnT, WgT, WgruB, biasS);
  hipMemsetAsync(hist, 0, 34 * sizeof(int), stream);
  hipMemsetAsync(psums, 0, (NGRAPH * GRUH + NGRAPH) * sizeof(float), stream);
  hist_kernel<<<196, 256, 0, stream>>>(deg, hist);
  scatter_kernel<<<196, 256, 0, stream>>>(deg, hist, resv, perm);
  xw_gemm_kernel<<<782, 256, 0, stream>>>(featB, WihB, biasS, XWb);
  lstm_kernel<<<1563, 256, 0, stream>>>(XWb, WhhB, biasS, nbr_idx, deg, perm, hTB);
  sage_kernel<<<782, 256, 0, stream>>>(featB, hTB, WsT, WnT, b_sage, deg, h1nB);
  agg_kernel<<<12500, 256, 0, stream>>>(h1nB, nbr_idx, deg, aggB);
  gc_gemm_kernel<<<782, 256, 0, stream>>>(aggB, WgT, b_gc, h2B);
  gru_kernel<<<782, 256, 0, stream>>>(h2B, WgruB, bih_gru, bhh_gru, gout);
  pool_partial_kernel<<<(NN + POOL_CHUNK - 1) / POOL_CHUNK, 256, 0, stream>>>(gout, gids, psums, pcnts);
  pool_final_kernel<<<2, 256, 0, stream>>>(psums, pcnts, W_cls, b_cls, (float*)d_out);
}

// Round 5
// 539.797 us; speedup vs baseline: 3.1673x; 1.2332x over previous
//
#include <hip/hip_runtime.h>
#include <hip/hip_bf16.h>

// GCN_71451075936314 on gfx950.
// R5: lstm restructured around the R4 counter evidence (gather-traffic-bound:
//     302MB FETCH from 1KB XW-row gathers; 4 waves = no latency hiding):
//     - XW precompute DELETED. Fused K-concat GEMM per step:
//         gates = x_t@Wih^T + h_{t-1}@Whh^T + bias   (x_t = feat[nbr[:,t]])
//       Gather is now 256B rows from the 12.8MB featB table (L2/LLC-resident).
//     - 512 thr / 8 waves / 32 nodes; wave owns 16 h-cols x 4 gates;
//       Wih+Whh B-frags BOTH pinned (128 VGPR/wave); x A-frags register-
//       prefetched one step ahead (per-lane 16B gathers, no LDS staging).
//     - Both per-step barriers are lgkm-only -> global prefetch stays in
//       flight across them. Hs XOR-swizzle kept (R4: 0 bank conflicts).
//     - scatter now sorts DESCENDING by degree (long blocks first, short tail).

#define NN     50000
#define HIDD   128
#define MAXD   16
#define NGRAPH 50
#define NCLSS  10
#define GRUH   32

typedef __attribute__((ext_vector_type(8))) short s16x8;    // 8 bf16 (4 VGPRs)
typedef __attribute__((ext_vector_type(4))) float f32x4;
typedef __hip_bfloat16 bf16;

#define MFMA16(a,b,c)  __builtin_amdgcn_mfma_f32_16x16x32_bf16((a),(b),(c),0,0,0)

__device__ __forceinline__ float bf2f(bf16 x) { return __bfloat162float(x); }
__device__ __forceinline__ bf16  f2bf(float x) { return __float2bfloat16(x); }
__device__ __forceinline__ s16x8 ldfrag(const bf16* p) { return *(const s16x8*)p; }

__device__ __forceinline__ float sigf(float x) {
  return __builtin_amdgcn_rcpf(1.0f + __expf(-x));
}
__device__ __forceinline__ float tanhf_(float x) {
  return 1.0f - 2.0f * __builtin_amdgcn_rcpf(1.0f + __expf(2.0f * x));
}

// barrier that drains LDS ops only — global loads (x prefetch) stay in flight
__device__ __forceinline__ void lgkm_barrier() {
  asm volatile("s_waitcnt lgkmcnt(0)\n\ts_barrier" ::: "memory");
}

// ---------------- prep: bf16 casts + weight transposes + bias fold ----------------
__global__ void prep_kernel(const float* __restrict__ feat, const float* __restrict__ Wih,
                            const float* __restrict__ Whh, const float* __restrict__ bih,
                            const float* __restrict__ bhh, const float* __restrict__ Wself,
                            const float* __restrict__ Wneigh, const float* __restrict__ Wgc,
                            const float* __restrict__ Wgru,
                            bf16* featB, bf16* WihB, bf16* WhhB, bf16* WsT, bf16* WnT,
                            bf16* WgT, bf16* WgruB, float* biasS) {
  const int nf = NN * HIDD;
  const int total = nf + 2 * 65536 + 3 * 16384 + 12288 + 512;
  int stride = gridDim.x * blockDim.x;
  for (int idx = blockIdx.x * blockDim.x + threadIdx.x; idx < total; idx += stride) {
    if (idx < nf) { featB[idx] = f2bf(feat[idx]); continue; }
    int j = idx - nf;
    if (j < 65536) { WihB[j] = f2bf(Wih[j]); continue; }
    j -= 65536;
    if (j < 65536) { WhhB[j] = f2bf(Whh[j]); continue; }
    j -= 65536;
    if (j < 16384) { int c = j >> 7, k = j & 127; WsT[j] = f2bf(Wself[k * HIDD + c]); continue; }
    j -= 16384;
    if (j < 16384) { int c = j >> 7, k = j & 127; WnT[j] = f2bf(Wneigh[k * HIDD + c]); continue; }
    j -= 16384;
    if (j < 16384) { int c = j >> 7, k = j & 127; WgT[j] = f2bf(Wgc[k * HIDD + c]); continue; }
    j -= 16384;
    if (j < 12288) { WgruB[j] = f2bf(Wgru[j]); continue; }
    j -= 12288;
    biasS[j] = bih[j] + bhh[j];
  }
}

// ---------------- counting sort by degree (DESCENDING): LDS hist ----------------
__global__ __launch_bounds__(256) void hist_kernel(const int* __restrict__ deg, int* hist) {
  __shared__ int lh[17];
  const int tid = threadIdx.x;
  if (tid < 17) lh[tid] = 0;
  __syncthreads();
  const int i = blockIdx.x * 256 + tid;
  if (i < NN) atomicAdd(&lh[deg[i]], 1);
  __syncthreads();
  if (tid < 17 && lh[tid]) atomicAdd(&hist[tid], lh[tid]);
}

__global__ __launch_bounds__(256) void scatter_kernel(const int* __restrict__ deg,
                                                      const int* __restrict__ hist,
                                                      int* __restrict__ resv,
                                                      int* __restrict__ perm) {
  __shared__ int lh[17], lbase[17], lpos[17];
  const int tid = threadIdx.x;
  if (tid < 17) { lh[tid] = 0; lpos[tid] = 0; }
  __syncthreads();
  const int i = blockIdx.x * 256 + tid;
  const int d = (i < NN) ? deg[i] : -1;
  if (d >= 0) atomicAdd(&lh[d], 1);
  __syncthreads();
  if (tid < 17) {
    int pre = 0;
    for (int k = tid + 1; k < 17; ++k) pre += hist[k];   // descending: larger degs first
    lbase[tid] = pre + (lh[tid] ? atomicAdd(&resv[tid], lh[tid]) : 0);
  }
  __syncthreads();
  if (d >= 0) {
    const int p = lbase[d] + atomicAdd(&lpos[d], 1);
    perm[p] = i;
  }
}

// ---------------- LSTM recurrence: 512 thr / 8 waves / 32 nodes ----------------
// Wave w owns h-cols [w*16, w*16+16) for ALL 4 gates (cols q*128 + w*16 + l15).
// B-frags of Wih AND Whh pinned (128 VGPR). x A-frags register-prefetched one
// step ahead via per-lane 16B gathers from featB. Hs xor-swizzled in LDS.
__global__ __launch_bounds__(512, 2) void lstm_kernel(const bf16* __restrict__ featB,
                                                      const bf16* __restrict__ WihB,
                                                      const bf16* __restrict__ WhhB,
                                                      const float* __restrict__ biasS,
                                                      const int* __restrict__ nbr_idx,
                                                      const int* __restrict__ deg,
                                                      const int* __restrict__ perm,
                                                      bf16* __restrict__ hTB) {
  __shared__ __align__(16) bf16 Hs[32 * 128];   // h tile, xor-swizzled, 8KB
  __shared__ int nbr_s[16 * 32];                // [t][row] transposed: conflict-free reads
  __shared__ int nodes_s[32];
  __shared__ int degs_s[32];

  const int tid = threadIdx.x;
  const int lane = tid & 63, w = tid >> 6;      // w = h-col block
  const int l15 = lane & 15, quad = lane >> 4;
  const int base = blockIdx.x * 32;
  const int colw = w * 16 + l15;                // this thread's h-col

  if (tid < 32) {
    const int gi = base + tid;
    const int nd = (gi < NN) ? perm[gi] : -1;
    nodes_s[tid] = nd;
    degs_s[tid] = (nd >= 0) ? deg[nd] : 0;
  }
  __syncthreads();
  for (int e = tid; e < 16 * 32; e += 512) {
    const int row = e & 31, t = e >> 5;
    const int nd = nodes_s[row];
    nbr_s[t * 32 + row] = (nd >= 0) ? nbr_idx[nd * MAXD + t] : 0;
  }
  for (int e = tid; e < 32 * 64; e += 512) ((unsigned int*)Hs)[e] = 0u;

  // B fragments, pinned so the compiler can't rematerialize them in the loop
  s16x8 Bi[4][4], Bh[4][4];
#pragma unroll
  for (int q = 0; q < 4; ++q) {
    const int col = q * 128 + colw;
#pragma unroll
    for (int kt = 0; kt < 4; ++kt) {
      Bi[q][kt] = ldfrag(WihB + col * HIDD + kt * 32 + quad * 8);
      Bh[q][kt] = ldfrag(WhhB + col * HIDD + kt * 32 + quad * 8);
      asm volatile("" : "+v"(Bi[q][kt]));
      asm volatile("" : "+v"(Bh[q][kt]));
    }
  }
  float biasv[4];
#pragma unroll
  for (int q = 0; q < 4; ++q) biasv[q] = biasS[q * 128 + colw];

  __syncthreads();                              // nbr_s, degs_s, Hs-zero visible
  const int maxdeg = degs_s[0];                 // descending sort -> first is block max

  int mydeg[2][4];
#pragma unroll
  for (int rt = 0; rt < 2; ++rt)
#pragma unroll
    for (int rr = 0; rr < 4; ++rr) mydeg[rt][rr] = degs_s[rt * 16 + quad * 4 + rr];

  // prefetch x A-frags for t=0: lane -> row rt*16+l15, k = kt*32+quad*8
  s16x8 xf[2][4];
#pragma unroll
  for (int rt = 0; rt < 2; ++rt) {
    const int nb0 = nbr_s[0 * 32 + rt * 16 + l15];
#pragma unroll
    for (int kt = 0; kt < 4; ++kt)
      xf[rt][kt] = ldfrag(featB + (size_t)nb0 * HIDD + kt * 32 + quad * 8);
  }

  float cst[2][4] = {{0.f, 0.f, 0.f, 0.f}, {0.f, 0.f, 0.f, 0.f}};

  for (int t = 0; t < maxdeg; ++t) {
    f32x4 acc[2][4];
#pragma unroll
    for (int rt = 0; rt < 2; ++rt)
#pragma unroll
      for (int q = 0; q < 4; ++q) acc[rt][q] = (f32x4){0.f, 0.f, 0.f, 0.f};

    // x-part: gates += x_t @ Wih^T
#pragma unroll
    for (int rt = 0; rt < 2; ++rt)
#pragma unroll
      for (int kt = 0; kt < 4; ++kt)
#pragma unroll
        for (int q = 0; q < 4; ++q)
          acc[rt][q] = MFMA16(xf[rt][kt], Bi[q][kt], acc[rt][q]);

    // prefetch x for t+1 (latency covered by h-part + elementwise)
    if (t + 1 < maxdeg) {
#pragma unroll
      for (int rt = 0; rt < 2; ++rt) {
        const int nb1 = nbr_s[(t + 1) * 32 + rt * 16 + l15];
#pragma unroll
        for (int kt = 0; kt < 4; ++kt)
          xf[rt][kt] = ldfrag(featB + (size_t)nb1 * HIDD + kt * 32 + quad * 8);
      }
    }

    // h-part: gates += h_{t-1} @ Whh^T   (skip at t=0: h0 = 0)
    if (t > 0) {
#pragma unroll
      for (int rt = 0; rt < 2; ++rt)
#pragma unroll
        for (int kt = 0; kt < 4; ++kt) {
          const int m = rt * 16 + l15;
          const int k = kt * 32 + quad * 8;
          const s16x8 ah = ldfrag(Hs + m * 128 + (k ^ (l15 * 8)));
#pragma unroll
          for (int q = 0; q < 4; ++q)
            acc[rt][q] = MFMA16(ah, Bh[q][kt], acc[rt][q]);
        }
    }
    lgkm_barrier();   // all waves' Hs reads complete before overwrite

    // elementwise LSTM cell (rows rt*16 + quad*4 + rr, col colw)
#pragma unroll
    for (int rt = 0; rt < 2; ++rt)
#pragma unroll
      for (int rr = 0; rr < 4; ++rr) {
        const int row = rt * 16 + quad * 4 + rr;
        const float g_i = acc[rt][0][rr] + biasv[0];
        const float g_f = acc[rt][1][rr] + biasv[1];
        const float g_g = acc[rt][2][rr] + biasv[2];
        const float g_o = acc[rt][3][rr] + biasv[3];
        const float iv = sigf(g_i), fv = sigf(g_f);
        const float gv = tanhf_(g_g), ov = sigf(g_o);
        const float cn = fv * cst[rt][rr] + iv * gv;
        const float hn = ov * tanhf_(cn);
        if (t < mydeg[rt][rr]) {
          cst[rt][rr] = cn;
          Hs[row * 128 + (colw ^ ((row & 15) * 8))] = f2bf(hn);
        }
      }
    lgkm_barrier();   // Hs writes visible for next step's h-part
  }

  // epilogue: Hs (swizzled) -> hTB
  for (int e = tid; e < 32 * 16; e += 512) {
    const int row = e >> 4, j = e & 15;
    const int nd = nodes_s[row];
    if (nd >= 0) {
      const s16x8 v = ldfrag(Hs + row * 128 + ((j * 8) ^ ((row & 15) * 8)));
      *(s16x8*)(hTB + (size_t)nd * HIDD + j * 8) = v;
    }
  }
}

// ------- SAGE: h1n = relu(feat@W_self + hT@W_neigh + b) * rsqrt(deg) -------
__global__ __launch_bounds__(256) void sage_kernel(const bf16* __restrict__ featB,
                                                   const bf16* __restrict__ hTB,
                                                   const bf16* __restrict__ WsT,
                                                   const bf16* __restrict__ WnT,
                                                   const float* __restrict__ b_sage,
                                                   const int* __restrict__ deg,
                                                   bf16* __restrict__ h1n) {
  const int lane = threadIdx.x & 63, wave = threadIdx.x >> 6;
  const int l15 = lane & 15, quad = lane >> 4;
  const int nb = blockIdx.x * 64 + wave * 16;
  int arow = nb + l15; if (arow >= NN) arow = NN - 1;
  s16x8 Fa[4], Ha[4];
#pragma unroll
  for (int kt = 0; kt < 4; ++kt) {
    Fa[kt] = ldfrag(featB + (size_t)arow * HIDD + kt * 32 + quad * 8);
    Ha[kt] = ldfrag(hTB + (size_t)arow * HIDD + kt * 32 + quad * 8);
  }
  int nodes[4]; float nrm[4];
#pragma unroll
  for (int r = 0; r < 4; ++r) {
    const int nd = nb + quad * 4 + r;
    nodes[r] = nd;
    nrm[r] = rsqrtf((float)deg[(nd < NN) ? nd : (NN - 1)]);
  }
  for (int ct = 0; ct < 8; ++ct) {
    const int col = ct * 16 + l15;
    f32x4 acc = {0.f, 0.f, 0.f, 0.f};
#pragma unroll
    for (int kt = 0; kt < 4; ++kt) {
      acc = MFMA16(Fa[kt], ldfrag(WsT + col * HIDD + kt * 32 + quad * 8), acc);
      acc = MFMA16(Ha[kt], ldfrag(WnT + col * HIDD + kt * 32 + quad * 8), acc);
    }
    const float bb = b_sage[col];
#pragma unroll
    for (int r = 0; r < 4; ++r)
      if (nodes[r] < NN) {
        const float v = fmaxf(acc[r] + bb, 0.f) * nrm[r];
        h1n[(size_t)nodes[r] * HIDD + col] = f2bf(v);
      }
  }
}

// ------- GraphConv aggregate: agg[n] = rsqrt(deg[n]) * sum_{t<deg} h1n[nbr[n,t]] -------
__global__ __launch_bounds__(256) void agg_kernel(const bf16* __restrict__ h1n,
                                                  const int* __restrict__ nbr_idx,
                                                  const int* __restrict__ deg,
                                                  bf16* __restrict__ aggB) {
  const int wave = threadIdx.x >> 6, lane = threadIdx.x & 63;
  const int node = blockIdx.x * 4 + wave;
  if (node >= NN) return;
  const int d = deg[node];
  const int idx_l = nbr_idx[node * MAXD + (lane & 15)];   // coalesced, broadcast via shfl
  const int c = lane * 2;
  float a0 = 0.f, a1 = 0.f;
  for (int t = 0; t < d; ++t) {
    const int nbr = __shfl(idx_l, t, 64);
    const __hip_bfloat162 v = *(const __hip_bfloat162*)(h1n + (size_t)nbr * HIDD + c);
    a0 += __bfloat162float(v.x);
    a1 += __bfloat162float(v.y);
  }
  const float nm = rsqrtf((float)d);
  aggB[(size_t)node * HIDD + c]     = f2bf(a0 * nm);
  aggB[(size_t)node * HIDD + c + 1] = f2bf(a1 * nm);
}

// ------- GraphConv GEMM: h2 = relu(agg @ W_gc + b_gc) -------
__global__ __launch_bounds__(256) void gc_gemm_kernel(const bf16* __restrict__ aggB,
                                                      const bf16* __restrict__ WgT,
                                                      const float* __restrict__ b_gc,
                                                      bf16* __restrict__ h2B) {
  const int lane = threadIdx.x & 63, wave = threadIdx.x >> 6;
  const int l15 = lane & 15, quad = lane >> 4;
  const int nb = blockIdx.x * 64 + wave * 16;
  int arow = nb + l15; if (arow >= NN) arow = NN - 1;
  s16x8 A[4];
#pragma unroll
  for (int kt = 0; kt < 4; ++kt) A[kt] = ldfrag(aggB + (size_t)arow * HIDD + kt * 32 + quad * 8);
  for (int ct = 0; ct < 8; ++ct) {
    const int col = ct * 16 + l15;
    f32x4 acc = {0.f, 0.f, 0.f, 0.f};
#pragma unroll
    for (int kt = 0; kt < 4; ++kt)
      acc = MFMA16(A[kt], ldfrag(WgT + col * HIDD + kt * 32 + quad * 8), acc);
    const float bb = b_gc[col];
#pragma unroll
    for (int r = 0; r < 4; ++r) {
      const int node = nb + quad * 4 + r;
      if (node < NN) h2B[(size_t)node * HIDD + col] = f2bf(fmaxf(acc[r] + bb, 0.f));
    }
  }
}

// ------- GRU (seq_len=1, h0=0): out = (1-z)*tanh(xn + r*bn) -------
__global__ __launch_bounds__(256) void gru_kernel(const bf16* __restrict__ h2B,
                                                  const bf16* __restrict__ WgruB,
                                                  const float* __restrict__ bih,
                                                  const float* __restrict__ bhh,
                                                  float* __restrict__ gout) {
  const int lane = threadIdx.x & 63, wave = threadIdx.x >> 6;
  const int l15 = lane & 15, quad = lane >> 4;
  const int nb = blockIdx.x * 64 + wave * 16;
  int arow = nb + l15; if (arow >= NN) arow = NN - 1;
  s16x8 A[4];
#pragma unroll
  for (int kt = 0; kt < 4; ++kt) A[kt] = ldfrag(h2B + (size_t)arow * HIDD + kt * 32 + quad * 8);
  f32x4 acc[6];
#pragma unroll
  for (int ct = 0; ct < 6; ++ct) {
    f32x4 a = {0.f, 0.f, 0.f, 0.f};
#pragma unroll
    for (int kt = 0; kt < 4; ++kt)
      a = MFMA16(A[kt], ldfrag(WgruB + (ct * 16 + l15) * HIDD + kt * 32 + quad * 8), a);
    acc[ct] = a;
  }
#pragma unroll
  for (int u = 0; u < 2; ++u) {
    const int cu = 16 * u + l15;
    const float br = bih[cu] + bhh[cu];
    const float bz = bih[32 + cu] + bhh[32 + cu];
    const float bni = bih[64 + cu];
    const float bnh = bhh[64 + cu];
#pragma unroll
    for (int r = 0; r < 4; ++r) {
      const int node = nb + quad * 4 + r;
      if (node < NN) {
        const float rv = sigf(acc[u][r] + br);
        const float zv = sigf(acc[2 + u][r] + bz);
        const float nv = tanhf_(acc[4 + u][r] + bni + rv * bnh);
        gout[(size_t)node * GRUH + cu] = (1.f - zv) * nv;
      }
    }
  }
}

// ------- two-phase per-graph mean pool + classifier -------
#define POOL_CHUNK 512
__global__ __launch_bounds__(256) void pool_partial_kernel(const float* __restrict__ gout,
                                                           const int* __restrict__ gids,
                                                           float* __restrict__ sums,
                                                           float* __restrict__ cnts) {
  __shared__ float ls[NGRAPH * GRUH];
  __shared__ float lc[NGRAPH];
  const int tid = threadIdx.x;
  for (int i = tid; i < NGRAPH * GRUH; i += 256) ls[i] = 0.f;
  if (tid < NGRAPH) lc[tid] = 0.f;
  __syncthreads();

  const int wave = tid >> 6, lane = tid & 63;
  const int c = lane & 31, half = lane >> 5;
  const int base = blockIdx.x * POOL_CHUNK + wave * (POOL_CHUNK / 8);

  float accv = 0.f, ccnt = 0.f;
  int curg = -1;
  for (int it = 0; it < POOL_CHUNK / 16; ++it) {
    const int n = base + it * 2 + half;
    if (n < NN) {
      const int g = gids[n];
      const float v = gout[(size_t)n * GRUH + c];
      if (g != curg) {
        if (curg >= 0) {
          atomicAdd(&ls[curg * GRUH + c], accv);
          if (c == 0) atomicAdd(&lc[curg], ccnt);
        }
        curg = g; accv = 0.f; ccnt = 0.f;
      }
      accv += v; ccnt += 1.f;
    }
  }
  if (curg >= 0) {
    atomicAdd(&ls[curg * GRUH + c], accv);
    if (c == 0) atomicAdd(&lc[curg], ccnt);
  }
  __syncthreads();
  for (int i = tid; i < NGRAPH * GRUH; i += 256)
    if (ls[i] != 0.f) atomicAdd(&sums[i], ls[i]);
  if (tid < NGRAPH && lc[tid] != 0.f) atomicAdd(&cnts[tid], lc[tid]);
}

__global__ __launch_bounds__(256) void pool_final_kernel(const float* __restrict__ sums,
                                                         const float* __restrict__ cnts,
                                                         const float* __restrict__ Wcls,
                                                         const float* __restrict__ bcls,
                                                         float* __restrict__ out) {
  const int idx = blockIdx.x * blockDim.x + threadIdx.x;
  if (idx >= NGRAPH * NCLSS) return;
  const int g = idx / NCLSS, k = idx % NCLSS;
  const float inv = 1.0f / cnts[g];
  float acc = bcls[k];
#pragma unroll
  for (int cc = 0; cc < GRUH; ++cc)
    acc += sums[g * GRUH + cc] * inv * Wcls[cc * NCLSS + k];
  out[idx] = acc;
}

extern "C" void kernel_launch(void* const* d_in, const int* in_sizes, int n_in,
                              void* d_out, int out_size, void* d_ws, size_t ws_size,
                              hipStream_t stream) {
  const float* feature  = (const float*)d_in[0];
  const int*   nbr_idx  = (const int*)d_in[1];
  const int*   deg      = (const int*)d_in[2];
  const int*   gids     = (const int*)d_in[3];
  const float* lstm_Wih = (const float*)d_in[4];
  const float* lstm_Whh = (const float*)d_in[5];
  const float* lstm_bih = (const float*)d_in[6];
  const float* lstm_bhh = (const float*)d_in[7];
  const float* W_self   = (const float*)d_in[8];
  const float* W_neigh  = (const float*)d_in[9];
  const float* b_sage   = (const float*)d_in[10];
  const float* W_gc     = (const float*)d_in[11];
  const float* b_gc     = (const float*)d_in[12];
  const float* Wih_gru  = (const float*)d_in[13];
  const float* bih_gru  = (const float*)d_in[14];
  const float* bhh_gru  = (const float*)d_in[15];
  const float* W_cls    = (const float*)d_in[16];
  const float* b_cls    = (const float*)d_in[17];

  // workspace: XW buffer eliminated; peak ~66 MB
  char* ws = (char*)d_ws;
  bf16*  featB = (bf16*)(ws + 0);           // [NN,128] 12.8MB (dead after sage)
  bf16*  hTB   = (bf16*)(ws + 12800000);    // [NN,128] (dead after sage)
  bf16*  h1nB  = (bf16*)(ws + 25600000);    // [NN,128] (dead after agg)
  bf16*  aggB  = (bf16*)(ws + 38400000);    // [NN,128] (dead after gc)
  bf16*  h2B   = (bf16*)(ws + 51200000);    // [NN,128]
  float* gout  = (float*)(ws + 12800000);   // alias hTB (dead after sage)
  const size_t wo = 64000000;
  bf16*  WihB  = (bf16*)(ws + wo);
  bf16*  WhhB  = (bf16*)(ws + wo + 131072);
  bf16*  WsT   = (bf16*)(ws + wo + 262144);
  bf16*  WnT   = (bf16*)(ws + wo + 294912);
  bf16*  WgT   = (bf16*)(ws + wo + 327680);
  bf16*  WgruB = (bf16*)(ws + wo + 360448);
  float* biasS = (float*)(ws + wo + 385024);
  int*   perm  = (int*)(ws + 65000000);
  int*   hist  = (int*)(ws + 65400000);     // [17]
  int*   resv  = hist + 17;                 // [17]
  float* psums = (float*)(ws + 65401216);   // [50][32]
  float* pcnts = psums + NGRAPH * GRUH;     // [50]

  prep_kernel<<<3072, 256, 0, stream>>>(feature, lstm_Wih, lstm_Whh, lstm_bih, lstm_bhh,
                                        W_self, W_neigh, W_gc, Wih_gru,
                                        featB, WihB, WhhB, WsT, WnT, WgT, WgruB, biasS);
  hipMemsetAsync(hist, 0, 34 * sizeof(int), stream);
  hipMemsetAsync(psums, 0, (NGRAPH * GRUH + NGRAPH) * sizeof(float), stream);
  hist_kernel<<<196, 256, 0, stream>>>(deg, hist);
  scatter_kernel<<<196, 256, 0, stream>>>(deg, hist, resv, perm);
  lstm_kernel<<<1563, 512, 0, stream>>>(featB, WihB, WhhB, biasS, nbr_idx, deg, perm, hTB);
  sage_kernel<<<782, 256, 0, stream>>>(featB, hTB, WsT, WnT, b_sage, deg, h1nB);
  agg_kernel<<<12500, 256, 0, stream>>>(h1nB, nbr_idx, deg, aggB);
  gc_gemm_kernel<<<782, 256, 0, stream>>>(aggB, WgT, b_gc, h2B);
  gru_kernel<<<782, 256, 0, stream>>>(h2B, WgruB, bih_gru, bhh_gru, gout);
  pool_partial_kernel<<<(NN + POOL_CHUNK - 1) / POOL_CHUNK, 256, 0, stream>>>(gout, gids, psums, pcnts);
  pool_final_kernel<<<2, 256, 0, stream>>>(psums, pcnts, W_cls, b_cls, (float*)d_out);
}

// Round 6
// 539.512 us; speedup vs baseline: 3.1689x; 1.0005x over previous
//
#include <hip/hip_runtime.h>
#include <hip/hip_bf16.h>

// GCN_71451075936314 on gfx950.
// R6: single change vs R5 — lstm __launch_bounds__(512,2) -> (512,1).
//     R5 evidence: VGPR_Count=128 (the ",2" was honored as 2 BLOCKS/CU ->
//     4 waves/SIMD -> 128-VGPR cap) while the kernel needs ~232 live regs
//     (Bi 64 + Bh 64 + xf 32 + acc 32 + misc). Result: ~61MB/dispatch of
//     scratch spill WRITES (WRITE_SIZE 73.8MB vs 12.8 ideal) + reloads on
//     the serial recurrence chain (~14k cyc/step). With min-1 the cap is
//     >=256: everything resident, zero spill, 8 waves/CU.

#define NN     50000
#define HIDD   128
#define MAXD   16
#define NGRAPH 50
#define NCLSS  10
#define GRUH   32

typedef __attribute__((ext_vector_type(8))) short s16x8;    // 8 bf16 (4 VGPRs)
typedef __attribute__((ext_vector_type(4))) float f32x4;
typedef __hip_bfloat16 bf16;

#define MFMA16(a,b,c)  __builtin_amdgcn_mfma_f32_16x16x32_bf16((a),(b),(c),0,0,0)

__device__ __forceinline__ float bf2f(bf16 x) { return __bfloat162float(x); }
__device__ __forceinline__ bf16  f2bf(float x) { return __float2bfloat16(x); }
__device__ __forceinline__ s16x8 ldfrag(const bf16* p) { return *(const s16x8*)p; }

__device__ __forceinline__ float sigf(float x) {
  return __builtin_amdgcn_rcpf(1.0f + __expf(-x));
}
__device__ __forceinline__ float tanhf_(float x) {
  return 1.0f - 2.0f * __builtin_amdgcn_rcpf(1.0f + __expf(2.0f * x));
}

// barrier that drains LDS ops only — global loads (x prefetch) stay in flight
__device__ __forceinline__ void lgkm_barrier() {
  asm volatile("s_waitcnt lgkmcnt(0)\n\ts_barrier" ::: "memory");
}

// ---------------- prep: bf16 casts + weight transposes + bias fold ----------------
__global__ void prep_kernel(const float* __restrict__ feat, const float* __restrict__ Wih,
                            const float* __restrict__ Whh, const float* __restrict__ bih,
                            const float* __restrict__ bhh, const float* __restrict__ Wself,
                            const float* __restrict__ Wneigh, const float* __restrict__ Wgc,
                            const float* __restrict__ Wgru,
                            bf16* featB, bf16* WihB, bf16* WhhB, bf16* WsT, bf16* WnT,
                            bf16* WgT, bf16* WgruB, float* biasS) {
  const int nf = NN * HIDD;
  const int total = nf + 2 * 65536 + 3 * 16384 + 12288 + 512;
  int stride = gridDim.x * blockDim.x;
  for (int idx = blockIdx.x * blockDim.x + threadIdx.x; idx < total; idx += stride) {
    if (idx < nf) { featB[idx] = f2bf(feat[idx]); continue; }
    int j = idx - nf;
    if (j < 65536) { WihB[j] = f2bf(Wih[j]); continue; }
    j -= 65536;
    if (j < 65536) { WhhB[j] = f2bf(Whh[j]); continue; }
    j -= 65536;
    if (j < 16384) { int c = j >> 7, k = j & 127; WsT[j] = f2bf(Wself[k * HIDD + c]); continue; }
    j -= 16384;
    if (j < 16384) { int c = j >> 7, k = j & 127; WnT[j] = f2bf(Wneigh[k * HIDD + c]); continue; }
    j -= 16384;
    if (j < 16384) { int c = j >> 7, k = j & 127; WgT[j] = f2bf(Wgc[k * HIDD + c]); continue; }
    j -= 16384;
    if (j < 12288) { WgruB[j] = f2bf(Wgru[j]); continue; }
    j -= 12288;
    biasS[j] = bih[j] + bhh[j];
  }
}

// ---------------- counting sort by degree (DESCENDING): LDS hist ----------------
__global__ __launch_bounds__(256) void hist_kernel(const int* __restrict__ deg, int* hist) {
  __shared__ int lh[17];
  const int tid = threadIdx.x;
  if (tid < 17) lh[tid] = 0;
  __syncthreads();
  const int i = blockIdx.x * 256 + tid;
  if (i < NN) atomicAdd(&lh[deg[i]], 1);
  __syncthreads();
  if (tid < 17 && lh[tid]) atomicAdd(&hist[tid], lh[tid]);
}

__global__ __launch_bounds__(256) void scatter_kernel(const int* __restrict__ deg,
                                                      const int* __restrict__ hist,
                                                      int* __restrict__ resv,
                                                      int* __restrict__ perm) {
  __shared__ int lh[17], lbase[17], lpos[17];
  const int tid = threadIdx.x;
  if (tid < 17) { lh[tid] = 0; lpos[tid] = 0; }
  __syncthreads();
  const int i = blockIdx.x * 256 + tid;
  const int d = (i < NN) ? deg[i] : -1;
  if (d >= 0) atomicAdd(&lh[d], 1);
  __syncthreads();
  if (tid < 17) {
    int pre = 0;
    for (int k = tid + 1; k < 17; ++k) pre += hist[k];   // descending: larger degs first
    lbase[tid] = pre + (lh[tid] ? atomicAdd(&resv[tid], lh[tid]) : 0);
  }
  __syncthreads();
  if (d >= 0) {
    const int p = lbase[d] + atomicAdd(&lpos[d], 1);
    perm[p] = i;
  }
}

// ---------------- LSTM recurrence: 512 thr / 8 waves / 32 nodes ----------------
// Wave w owns h-cols [w*16, w*16+16) for ALL 4 gates (cols q*128 + w*16 + l15).
// B-frags of Wih AND Whh pinned (128 VGPR). x A-frags register-prefetched one
// step ahead via per-lane 16B gathers from featB. Hs xor-swizzled in LDS.
// launch_bounds (512,1): >=256 VGPR cap -> ~232 live regs resident, no spill.
__global__ __launch_bounds__(512, 1) void lstm_kernel(const bf16* __restrict__ featB,
                                                      const bf16* __restrict__ WihB,
                                                      const bf16* __restrict__ WhhB,
                                                      const float* __restrict__ biasS,
                                                      const int* __restrict__ nbr_idx,
                                                      const int* __restrict__ deg,
                                                      const int* __restrict__ perm,
                                                      bf16* __restrict__ hTB) {
  __shared__ __align__(16) bf16 Hs[32 * 128];   // h tile, xor-swizzled, 8KB
  __shared__ int nbr_s[16 * 32];                // [t][row] transposed: conflict-free reads
  __shared__ int nodes_s[32];
  __shared__ int degs_s[32];

  const int tid = threadIdx.x;
  const int lane = tid & 63, w = tid >> 6;      // w = h-col block
  const int l15 = lane & 15, quad = lane >> 4;
  const int base = blockIdx.x * 32;
  const int colw = w * 16 + l15;                // this thread's h-col

  if (tid < 32) {
    const int gi = base + tid;
    const int nd = (gi < NN) ? perm[gi] : -1;
    nodes_s[tid] = nd;
    degs_s[tid] = (nd >= 0) ? deg[nd] : 0;
  }
  __syncthreads();
  for (int e = tid; e < 16 * 32; e += 512) {
    const int row = e & 31, t = e >> 5;
    const int nd = nodes_s[row];
    nbr_s[t * 32 + row] = (nd >= 0) ? nbr_idx[nd * MAXD + t] : 0;
  }
  for (int e = tid; e < 32 * 64; e += 512) ((unsigned int*)Hs)[e] = 0u;

  // B fragments, pinned so the compiler can't rematerialize them in the loop
  s16x8 Bi[4][4], Bh[4][4];
#pragma unroll
  for (int q = 0; q < 4; ++q) {
    const int col = q * 128 + colw;
#pragma unroll
    for (int kt = 0; kt < 4; ++kt) {
      Bi[q][kt] = ldfrag(WihB + col * HIDD + kt * 32 + quad * 8);
      Bh[q][kt] = ldfrag(WhhB + col * HIDD + kt * 32 + quad * 8);
      asm volatile("" : "+v"(Bi[q][kt]));
      asm volatile("" : "+v"(Bh[q][kt]));
    }
  }
  float biasv[4];
#pragma unroll
  for (int q = 0; q < 4; ++q) biasv[q] = biasS[q * 128 + colw];

  __syncthreads();                              // nbr_s, degs_s, Hs-zero visible
  const int maxdeg = degs_s[0];                 // descending sort -> first is block max

  int mydeg[2][4];
#pragma unroll
  for (int rt = 0; rt < 2; ++rt)
#pragma unroll
    for (int rr = 0; rr < 4; ++rr) mydeg[rt][rr] = degs_s[rt * 16 + quad * 4 + rr];

  // prefetch x A-frags for t=0: lane -> row rt*16+l15, k = kt*32+quad*8
  s16x8 xf[2][4];
#pragma unroll
  for (int rt = 0; rt < 2; ++rt) {
    const int nb0 = nbr_s[0 * 32 + rt * 16 + l15];
#pragma unroll
    for (int kt = 0; kt < 4; ++kt)
      xf[rt][kt] = ldfrag(featB + (size_t)nb0 * HIDD + kt * 32 + quad * 8);
  }

  float cst[2][4] = {{0.f, 0.f, 0.f, 0.f}, {0.f, 0.f, 0.f, 0.f}};

  for (int t = 0; t < maxdeg; ++t) {
    f32x4 acc[2][4];
#pragma unroll
    for (int rt = 0; rt < 2; ++rt)
#pragma unroll
      for (int q = 0; q < 4; ++q) acc[rt][q] = (f32x4){0.f, 0.f, 0.f, 0.f};

    // x-part: gates += x_t @ Wih^T
#pragma unroll
    for (int rt = 0; rt < 2; ++rt)
#pragma unroll
      for (int kt = 0; kt < 4; ++kt)
#pragma unroll
        for (int q = 0; q < 4; ++q)
          acc[rt][q] = MFMA16(xf[rt][kt], Bi[q][kt], acc[rt][q]);

    // prefetch x for t+1 (latency covered by h-part + elementwise)
    if (t + 1 < maxdeg) {
#pragma unroll
      for (int rt = 0; rt < 2; ++rt) {
        const int nb1 = nbr_s[(t + 1) * 32 + rt * 16 + l15];
#pragma unroll
        for (int kt = 0; kt < 4; ++kt)
          xf[rt][kt] = ldfrag(featB + (size_t)nb1 * HIDD + kt * 32 + quad * 8);
      }
    }

    // h-part: gates += h_{t-1} @ Whh^T   (skip at t=0: h0 = 0)
    if (t > 0) {
#pragma unroll
      for (int rt = 0; rt < 2; ++rt)
#pragma unroll
        for (int kt = 0; kt < 4; ++kt) {
          const int m = rt * 16 + l15;
          const int k = kt * 32 + quad * 8;
          const s16x8 ah = ldfrag(Hs + m * 128 + (k ^ (l15 * 8)));
#pragma unroll
          for (int q = 0; q < 4; ++q)
            acc[rt][q] = MFMA16(ah, Bh[q][kt], acc[rt][q]);
        }
    }
    lgkm_barrier();   // all waves' Hs reads complete before overwrite

    // elementwise LSTM cell (rows rt*16 + quad*4 + rr, col colw)
#pragma unroll
    for (int rt = 0; rt < 2; ++rt)
#pragma unroll
      for (int rr = 0; rr < 4; ++rr) {
        const int row = rt * 16 + quad * 4 + rr;
        const float g_i = acc[rt][0][rr] + biasv[0];
        const float g_f = acc[rt][1][rr] + biasv[1];
        const float g_g = acc[rt][2][rr] + biasv[2];
        const float g_o = acc[rt][3][rr] + biasv[3];
        const float iv = sigf(g_i), fv = sigf(g_f);
        const float gv = tanhf_(g_g), ov = sigf(g_o);
        const float cn = fv * cst[rt][rr] + iv * gv;
        const float hn = ov * tanhf_(cn);
        if (t < mydeg[rt][rr]) {
          cst[rt][rr] = cn;
          Hs[row * 128 + (colw ^ ((row & 15) * 8))] = f2bf(hn);
        }
      }
    lgkm_barrier();   // Hs writes visible for next step's h-part
  }

  // epilogue: Hs (swizzled) -> hTB
  for (int e = tid; e < 32 * 16; e += 512) {
    const int row = e >> 4, j = e & 15;
    const int nd = nodes_s[row];
    if (nd >= 0) {
      const s16x8 v = ldfrag(Hs + row * 128 + ((j * 8) ^ ((row & 15) * 8)));
      *(s16x8*)(hTB + (size_t)nd * HIDD + j * 8) = v;
    }
  }
}

// ------- SAGE: h1n = relu(feat@W_self + hT@W_neigh + b) * rsqrt(deg) -------
__global__ __launch_bounds__(256) void sage_kernel(const bf16* __restrict__ featB,
                                                   const bf16* __restrict__ hTB,
                                                   const bf16* __restrict__ WsT,
                                                   const bf16* __restrict__ WnT,
                                                   const float* __restrict__ b_sage,
                                                   const int* __restrict__ deg,
                                                   bf16* __restrict__ h1n) {
  const int lane = threadIdx.x & 63, wave = threadIdx.x >> 6;
  const int l15 = lane & 15, quad = lane >> 4;
  const int nb = blockIdx.x * 64 + wave * 16;
  int arow = nb + l15; if (arow >= NN) arow = NN - 1;
  s16x8 Fa[4], Ha[4];
#pragma unroll
  for (int kt = 0; kt < 4; ++kt) {
    Fa[kt] = ldfrag(featB + (size_t)arow * HIDD + kt * 32 + quad * 8);
    Ha[kt] = ldfrag(hTB + (size_t)arow * HIDD + kt * 32 + quad * 8);
  }
  int nodes[4]; float nrm[4];
#pragma unroll
  for (int r = 0; r < 4; ++r) {
    const int nd = nb + quad * 4 + r;
    nodes[r] = nd;
    nrm[r] = rsqrtf((float)deg[(nd < NN) ? nd : (NN - 1)]);
  }
  for (int ct = 0; ct < 8; ++ct) {
    const int col = ct * 16 + l15;
    f32x4 acc = {0.f, 0.f, 0.f, 0.f};
#pragma unroll
    for (int kt = 0; kt < 4; ++kt) {
      acc = MFMA16(Fa[kt], ldfrag(WsT + col * HIDD + kt * 32 + quad * 8), acc);
      acc = MFMA16(Ha[kt], ldfrag(WnT + col * HIDD + kt * 32 + quad * 8), acc);
    }
    const float bb = b_sage[col];
#pragma unroll
    for (int r = 0; r < 4; ++r)
      if (nodes[r] < NN) {
        const float v = fmaxf(acc[r] + bb, 0.f) * nrm[r];
        h1n[(size_t)nodes[r] * HIDD + col] = f2bf(v);
      }
  }
}

// ------- GraphConv aggregate: agg[n] = rsqrt(deg[n]) * sum_{t<deg} h1n[nbr[n,t]] -------
__global__ __launch_bounds__(256) void agg_kernel(const bf16* __restrict__ h1n,
                                                  const int* __restrict__ nbr_idx,
                                                  const int* __restrict__ deg,
                                                  bf16* __restrict__ aggB) {
  const int wave = threadIdx.x >> 6, lane = threadIdx.x & 63;
  const int node = blockIdx.x * 4 + wave;
  if (node >= NN) return;
  const int d = deg[node];
  const int idx_l = nbr_idx[node * MAXD + (lane & 15)];   // coalesced, broadcast via shfl
  const int c = lane * 2;
  float a0 = 0.f, a1 = 0.f;
  for (int t = 0; t < d; ++t) {
    const int nbr = __shfl(idx_l, t, 64);
    const __hip_bfloat162 v = *(const __hip_bfloat162*)(h1n + (size_t)nbr * HIDD + c);
    a0 += __bfloat162float(v.x);
    a1 += __bfloat162float(v.y);
  }
  const float nm = rsqrtf((float)d);
  aggB[(size_t)node * HIDD + c]     = f2bf(a0 * nm);
  aggB[(size_t)node * HIDD + c + 1] = f2bf(a1 * nm);
}

// ------- GraphConv GEMM: h2 = relu(agg @ W_gc + b_gc) -------
__global__ __launch_bounds__(256) void gc_gemm_kernel(const bf16* __restrict__ aggB,
                                                      const bf16* __restrict__ WgT,
                                                      const float* __restrict__ b_gc,
                                                      bf16* __restrict__ h2B) {
  const int lane = threadIdx.x & 63, wave = threadIdx.x >> 6;
  const int l15 = lane & 15, quad = lane >> 4;
  const int nb = blockIdx.x * 64 + wave * 16;
  int arow = nb + l15; if (arow >= NN) arow = NN - 1;
  s16x8 A[4];
#pragma unroll
  for (int kt = 0; kt < 4; ++kt) A[kt] = ldfrag(aggB + (size_t)arow * HIDD + kt * 32 + quad * 8);
  for (int ct = 0; ct < 8; ++ct) {
    const int col = ct * 16 + l15;
    f32x4 acc = {0.f, 0.f, 0.f, 0.f};
#pragma unroll
    for (int kt = 0; kt < 4; ++kt)
      acc = MFMA16(A[kt], ldfrag(WgT + col * HIDD + kt * 32 + quad * 8), acc);
    const float bb = b_gc[col];
#pragma unroll
    for (int r = 0; r < 4; ++r) {
      const int node = nb + quad * 4 + r;
      if (node < NN) h2B[(size_t)node * HIDD + col] = f2bf(fmaxf(acc[r] + bb, 0.f));
    }
  }
}

// ------- GRU (seq_len=1, h0=0): out = (1-z)*tanh(xn + r*bn) -------
__global__ __launch_bounds__(256) void gru_kernel(const bf16* __restrict__ h2B,
                                                  const bf16* __restrict__ WgruB,
                                                  const float* __restrict__ bih,
                                                  const float* __restrict__ bhh,
                                                  float* __restrict__ gout) {
  const int lane = threadIdx.x & 63, wave = threadIdx.x >> 6;
  const int l15 = lane & 15, quad = lane >> 4;
  const int nb = blockIdx.x * 64 + wave * 16;
  int arow = nb + l15; if (arow >= NN) arow = NN - 1;
  s16x8 A[4];
#pragma unroll
  for (int kt = 0; kt < 4; ++kt) A[kt] = ldfrag(h2B + (size_t)arow * HIDD + kt * 32 + quad * 8);
  f32x4 acc[6];
#pragma unroll
  for (int ct = 0; ct < 6; ++ct) {
    f32x4 a = {0.f, 0.f, 0.f, 0.f};
#pragma unroll
    for (int kt = 0; kt < 4; ++kt)
      a = MFMA16(A[kt], ldfrag(WgruB + (ct * 16 + l15) * HIDD + kt * 32 + quad * 8), a);
    acc[ct] = a;
  }
#pragma unroll
  for (int u = 0; u < 2; ++u) {
    const int cu = 16 * u + l15;
    const float br = bih[cu] + bhh[cu];
    const float bz = bih[32 + cu] + bhh[32 + cu];
    const float bni = bih[64 + cu];
    const float bnh = bhh[64 + cu];
#pragma unroll
    for (int r = 0; r < 4; ++r) {
      const int node = nb + quad * 4 + r;
      if (node < NN) {
        const float rv = sigf(acc[u][r] + br);
        const float zv = sigf(acc[2 + u][r] + bz);
        const float nv = tanhf_(acc[4 + u][r] + bni + rv * bnh);
        gout[(size_t)node * GRUH + cu] = (1.f - zv) * nv;
      }
    }
  }
}

// ------- two-phase per-graph mean pool + classifier -------
#define POOL_CHUNK 512
__global__ __launch_bounds__(256) void pool_partial_kernel(const float* __restrict__ gout,
                                                           const int* __restrict__ gids,
                                                           float* __restrict__ sums,
                                                           float* __restrict__ cnts) {
  __shared__ float ls[NGRAPH * GRUH];
  __shared__ float lc[NGRAPH];
  const int tid = threadIdx.x;
  for (int i = tid; i < NGRAPH * GRUH; i += 256) ls[i] = 0.f;
  if (tid < NGRAPH) lc[tid] = 0.f;
  __syncthreads();

  const int wave = tid >> 6, lane = tid & 63;
  const int c = lane & 31, half = lane >> 5;
  const int base = blockIdx.x * POOL_CHUNK + wave * (POOL_CHUNK / 8);

  float accv = 0.f, ccnt = 0.f;
  int curg = -1;
  for (int it = 0; it < POOL_CHUNK / 16; ++it) {
    const int n = base + it * 2 + half;
    if (n < NN) {
      const int g = gids[n];
      const float v = gout[(size_t)n * GRUH + c];
      if (g != curg) {
        if (curg >= 0) {
          atomicAdd(&ls[curg * GRUH + c], accv);
          if (c == 0) atomicAdd(&lc[curg], ccnt);
        }
        curg = g; accv = 0.f; ccnt = 0.f;
      }
      accv += v; ccnt += 1.f;
    }
  }
  if (curg >= 0) {
    atomicAdd(&ls[curg * GRUH + c], accv);
    if (c == 0) atomicAdd(&lc[curg], ccnt);
  }
  __syncthreads();
  for (int i = tid; i < NGRAPH * GRUH; i += 256)
    if (ls[i] != 0.f) atomicAdd(&sums[i], ls[i]);
  if (tid < NGRAPH && lc[tid] != 0.f) atomicAdd(&cnts[tid], lc[tid]);
}

__global__ __launch_bounds__(256) void pool_final_kernel(const float* __restrict__ sums,
                                                         const float* __restrict__ cnts,
                                                         const float* __restrict__ Wcls,
                                                         const float* __restrict__ bcls,
                                                         float* __restrict__ out) {
  const int idx = blockIdx.x * blockDim.x + threadIdx.x;
  if (idx >= NGRAPH * NCLSS) return;
  const int g = idx / NCLSS, k = idx % NCLSS;
  const float inv = 1.0f / cnts[g];
  float acc = bcls[k];
#pragma unroll
  for (int cc = 0; cc < GRUH; ++cc)
    acc += sums[g * GRUH + cc] * inv * Wcls[cc * NCLSS + k];
  out[idx] = acc;
}

extern "C" void kernel_launch(void* const* d_in, const int* in_sizes, int n_in,
                              void* d_out, int out_size, void* d_ws, size_t ws_size,
                              hipStream_t stream) {
  const float* feature  = (const float*)d_in[0];
  const int*   nbr_idx  = (const int*)d_in[1];
  const int*   deg      = (const int*)d_in[2];
  const int*   gids     = (const int*)d_in[3];
  const float* lstm_Wih = (const float*)d_in[4];
  const float* lstm_Whh = (const float*)d_in[5];
  const float* lstm_bih = (const float*)d_in[6];
  const float* lstm_bhh = (const float*)d_in[7];
  const float* W_self   = (const float*)d_in[8];
  const float* W_neigh  = (const float*)d_in[9];
  const float* b_sage   = (const float*)d_in[10];
  const float* W_gc     = (const float*)d_in[11];
  const float* b_gc     = (const float*)d_in[12];
  const float* Wih_gru  = (const float*)d_in[13];
  const float* bih_gru  = (const float*)d_in[14];
  const float* bhh_gru  = (const float*)d_in[15];
  const float* W_cls    = (const float*)d_in[16];
  const float* b_cls    = (const float*)d_in[17];

  // workspace: peak ~66 MB
  char* ws = (char*)d_ws;
  bf16*  featB = (bf16*)(ws + 0);           // [NN,128] 12.8MB (dead after sage)
  bf16*  hTB   = (bf16*)(ws + 12800000);    // [NN,128] (dead after sage)
  bf16*  h1nB  = (bf16*)(ws + 25600000);    // [NN,128] (dead after agg)
  bf16*  aggB  = (bf16*)(ws + 38400000);    // [NN,128] (dead after gc)
  bf16*  h2B   = (bf16*)(ws + 51200000);    // [NN,128]
  float* gout  = (float*)(ws + 12800000);   // alias hTB (dead after sage)
  const size_t wo = 64000000;
  bf16*  WihB  = (bf16*)(ws + wo);
  bf16*  WhhB  = (bf16*)(ws + wo + 131072);
  bf16*  WsT   = (bf16*)(ws + wo + 262144);
  bf16*  WnT   = (bf16*)(ws + wo + 294912);
  bf16*  WgT   = (bf16*)(ws + wo + 327680);
  bf16*  WgruB = (bf16*)(ws + wo + 360448);
  float* biasS = (float*)(ws + wo + 385024);
  int*   perm  = (int*)(ws + 65000000);
  int*   hist  = (int*)(ws + 65400000);     // [17]
  int*   resv  = hist + 17;                 // [17]
  float* psums = (float*)(ws + 65401216);   // [50][32]
  float* pcnts = psums + NGRAPH * GRUH;     // [50]

  prep_kernel<<<3072, 256, 0, stream>>>(feature, lstm_Wih, lstm_Whh, lstm_bih, lstm_bhh,
                                        W_self, W_neigh, W_gc, Wih_gru,
                                        featB, WihB, WhhB, WsT, WnT, WgT, WgruB, biasS);
  hipMemsetAsync(hist, 0, 34 * sizeof(int), stream);
  hipMemsetAsync(psums, 0, (NGRAPH * GRUH + NGRAPH) * sizeof(float), stream);
  hist_kernel<<<196, 256, 0, stream>>>(deg, hist);
  scatter_kernel<<<196, 256, 0, stream>>>(deg, hist, resv, perm);
  lstm_kernel<<<1563, 512, 0, stream>>>(featB, WihB, WhhB, biasS, nbr_idx, deg, perm, hTB);
  sage_kernel<<<782, 256, 0, stream>>>(featB, hTB, WsT, WnT, b_sage, deg, h1nB);
  agg_kernel<<<12500, 256, 0, stream>>>(h1nB, nbr_idx, deg, aggB);
  gc_gemm_kernel<<<782, 256, 0, stream>>>(aggB, WgT, b_gc, h2B);
  gru_kernel<<<782, 256, 0, stream>>>(h2B, WgruB, bih_gru, bhh_gru, gout);
  pool_partial_kernel<<<(NN + POOL_CHUNK - 1) / POOL_CHUNK, 256, 0, stream>>>(gout, gids, psums, pcnts);
  pool_final_kernel<<<2, 256, 0, stream>>>(psums, pcnts, W_cls, b_cls, (float*)d_out);
}